// Round 6
// baseline (374.770 us; speedup 1.0000x reference)
//
#include <hip/hip_runtime.h>
#include <hip/hip_bf16.h>
#include <math.h>

#define NODES 50000
#define NEDGE 800000
#define NBLK_SCAN ((NODES + 255) / 256)   // 196

typedef __bf16 bf16_t;
typedef __bf16 bf16x8 __attribute__((ext_vector_type(8)));
typedef float floatx4 __attribute__((ext_vector_type(4)));

__device__ __forceinline__ float bfbits2f(unsigned int hi16) {
    union { unsigned int u; float f; } c; c.u = hi16; return c.f;
}
__device__ __forceinline__ unsigned short f2bfbits(float f) {
    bf16_t b = (bf16_t)f; unsigned short u;
    __builtin_memcpy(&u, &b, 2); return u;
}

// act: 0=none, 1=relu, 2=gelu(tanh-approx, fast exp), 3=softplus(fast)
__device__ __forceinline__ float act_rt(float v, int act) {
    if (act == 1) return fmaxf(v, 0.f);
    if (act == 2) {
        float w = 0.79788456f * (v + 0.044715f * v * v * v);
        float e = __expf(2.f * w);
        float th = 1.f - 2.f / (e + 1.f);
        return 0.5f * v * (1.f + th);
    }
    if (act == 3) return fmaxf(v, 0.f) + __logf(1.f + __expf(-fabsf(v)));
    return v;
}

// ---------------------------------------------------------------------------
// Weight prep: 9 matrices W[k][n] fp32 -> Wt[n][k] bf16 (transposed)
// ---------------------------------------------------------------------------
__global__ __launch_bounds__(256) void prep_weights(
    const float* __restrict__ w0, const float* __restrict__ w1,
    const float* __restrict__ w2, const float* __restrict__ w3,
    const float* __restrict__ w4, const float* __restrict__ w5,
    const float* __restrict__ w6, const float* __restrict__ w7,
    const float* __restrict__ w8, bf16_t* __restrict__ wt)
{
    const float* Ws[9] = {w0, w1, w2, w3, w4, w5, w6, w7, w8};
    const float* W = Ws[blockIdx.x];
    bf16_t* o = wt + blockIdx.x * 16384;
    for (int idx = threadIdx.x; idx < 16384; idx += 256) {
        int k = idx >> 7, n = idx & 127;
        o[n * 128 + k] = (bf16_t)W[idx];
    }
}

// ---------------------------------------------------------------------------
// GEMM building blocks, 64-row tile structure (48 KB LDS -> 3 blocks/CU).
// Bs: 128x128 bf16 weight, XOR-swizzled. Csw: 64x128 bf16 bounce tile.
// ---------------------------------------------------------------------------
__device__ __forceinline__ void load_w_regs(const bf16_t* __restrict__ W,
                                            uint4 (&wr)[8], int t)
{
    for (int i = 0; i < 8; ++i) {
        int c = t + i * 256;
        int row = c >> 4, g = c & 15;
        wr[i] = *(const uint4*)(W + row * 128 + g * 8);
    }
}
__device__ __forceinline__ void store_w_regs(const uint4 (&wr)[8],
                                             bf16_t* Bs, int t)
{
    for (int i = 0; i < 8; ++i) {
        int c = t + i * 256;
        int row = c >> 4, g = c & 15;
        *(uint4*)&Bs[row * 128 + ((g ^ (row & 15)) * 8)] = wr[i];
    }
}
__device__ __forceinline__ void afrag_gbf16(const bf16_t* __restrict__ A,
        bf16x8 (&af)[4], int r0, int lane, int wave, int M)
{
    int gr = r0 + wave * 16 + (lane & 15);
    gr = min(gr, M - 1);
    const bf16_t* p = A + (size_t)gr * 128 + (lane >> 4) * 8;
    for (int kc = 0; kc < 4; ++kc)
        af[kc] = *(const bf16x8*)(p + kc * 32);
}
__device__ __forceinline__ void kloop64(const bf16x8 (&af)[4], const bf16_t* Bs,
                                        floatx4 (&acc)[8], int l15, int quad)
{
    for (int ni = 0; ni < 8; ++ni)
        for (int r = 0; r < 4; ++r) acc[ni][r] = 0.f;
    for (int kc = 0; kc < 4; ++kc) {
        int kg = kc * 4 + quad;
        bf16x8 b[8];
        for (int ni = 0; ni < 8; ++ni) {
            int row = ni * 16 + l15;
            b[ni] = *(const bf16x8*)&Bs[row * 128 + ((kg ^ l15) * 8)];
        }
        for (int ni = 0; ni < 8; ++ni)
            acc[ni] = __builtin_amdgcn_mfma_f32_16x16x32_bf16(
                af[kc], b[ni], acc[ni], 0, 0, 0);
    }
}
__device__ __forceinline__ void write_Csw(bf16_t* Csw, floatx4 (&acc)[8],
        const float (&bias_r)[8], int lane, int wave, int act)
{
    const int l15 = lane & 15, quad = lane >> 4;
    for (int ni = 0; ni < 8; ++ni) {
        int col = ni * 16 + l15;
        for (int r = 0; r < 4; ++r) {
            int row = wave * 16 + quad * 4 + r;
            float v = act_rt(acc[ni][r] + bias_r[ni], act);
            Csw[row * 128 + (((col >> 3) ^ (row & 15)) << 3) + (col & 7)] = (bf16_t)v;
        }
    }
}
__device__ __forceinline__ void afrag_Csw(const bf16_t* Csw, bf16x8 (&af)[4],
                                          int lane, int wave)
{
    int l15 = lane & 15, quad = lane >> 4;
    int row = wave * 16 + l15;
    for (int kc = 0; kc < 4; ++kc) {
        int kg = kc * 4 + quad;
        af[kc] = *(const bf16x8*)&Csw[row * 128 + ((kg ^ l15) * 8)];
    }
}
__device__ __forceinline__ void copy_Csw_out(const bf16_t* Csw,
        bf16_t* __restrict__ out, int t, int r0, int M)
{
    for (int i = 0; i < 4; ++i) {
        int c = t + i * 256;
        int row = c >> 4, g = c & 15;
        int gr = r0 + row;
        if (gr < M)
            *(uint4*)(out + (size_t)gr * 128 + g * 8) =
                *(const uint4*)&Csw[row * 128 + ((g ^ (row & 15)) * 8)];
    }
}

// ---------------------------------------------------------------------------
// Fused MLP: per 64-row tile compute h (+write), LN->xres, then all 3
// branches (alpha/beta/gamma) with h A-fragments held in registers.
// ---------------------------------------------------------------------------
__global__ __launch_bounds__(256, 3) void mlp_all(
    const float* __restrict__ x, const bf16_t* __restrict__ wt,
    const float* __restrict__ b_lin,
    const float* __restrict__ ba1, const float* __restrict__ ba2,
    const float* __restrict__ bb1, const float* __restrict__ bb2,
    const float* __restrict__ bg1, const float* __restrict__ bg2,
    const float* __restrict__ ln_g, const float* __restrict__ ln_b,
    bf16_t* __restrict__ h, bf16_t* __restrict__ xres,
    bf16_t* __restrict__ al, bf16_t* __restrict__ be, bf16_t* __restrict__ ga,
    int M)
{
    __shared__ __align__(16) char smem[49152];
    bf16_t* Bs  = (bf16_t*)smem;
    bf16_t* Csw = (bf16_t*)(smem + 32768);
    const int t = threadIdx.x;
    const int r0 = blockIdx.x * 64;
    const int lane = t & 63, wave = t >> 6, l15 = lane & 15, quad = lane >> 4;
    uint4 wr[8];
    bf16x8 af[4], af_h[4];
    floatx4 acc[8];

    // ---- stage 0: h = x@W_lin + b_lin (A from fp32 x)
    {
        int gr = min(r0 + wave * 16 + l15, M - 1);
        const float* p = x + (size_t)gr * 128 + quad * 8;
        for (int kc = 0; kc < 4; ++kc) {
            float4 u0 = *(const float4*)(p + kc * 32);
            float4 u1 = *(const float4*)(p + kc * 32 + 4);
            bf16x8 f;
            f[0] = (bf16_t)u0.x; f[1] = (bf16_t)u0.y;
            f[2] = (bf16_t)u0.z; f[3] = (bf16_t)u0.w;
            f[4] = (bf16_t)u1.x; f[5] = (bf16_t)u1.y;
            f[6] = (bf16_t)u1.z; f[7] = (bf16_t)u1.w;
            af[kc] = f;
        }
    }
    load_w_regs(wt, wr, t);
    store_w_regs(wr, Bs, t);
    __syncthreads();
    {
        float bias_r[8];
        for (int ni = 0; ni < 8; ++ni) bias_r[ni] = b_lin[ni * 16 + l15];
        kloop64(af, Bs, acc, l15, quad);
        __syncthreads();                 // all waves done with Bs; Csw free
        write_Csw(Csw, acc, bias_r, lane, wave, 0);
    }
    __syncthreads();                     // Csw(h) ready

    afrag_Csw(Csw, af_h, lane, wave);    // keep h fragment in regs

    // LN from Csw (4 threads/row); write h and xres coalesced
    {
        int row = t >> 2, p4 = t & 3;
        int gr = r0 + row;
        uint4 raw[4];
        float vals[32];
        float s = 0.f, sq = 0.f;
        for (int i = 0; i < 4; ++i) {
            int lg = p4 * 4 + i;
            raw[i] = *(const uint4*)&Csw[row * 128 + ((lg ^ (row & 15)) * 8)];
            const unsigned* u = (const unsigned*)&raw[i];
            for (int k = 0; k < 4; ++k) {
                float f0 = bfbits2f(u[k] << 16);
                float f1 = bfbits2f(u[k] & 0xffff0000u);
                vals[i * 8 + k * 2] = f0; vals[i * 8 + k * 2 + 1] = f1;
                s += f0 + f1; sq += f0 * f0 + f1 * f1;
            }
        }
        s += __shfl_xor(s, 1, 64);  sq += __shfl_xor(sq, 1, 64);
        s += __shfl_xor(s, 2, 64);  sq += __shfl_xor(sq, 2, 64);
        float m   = s * (1.f / 128.f);
        float var = fmaxf(sq * (1.f / 128.f) - m * m, 0.f);
        float rs  = rsqrtf(var + 1e-5f);
        if (gr < M) {
            for (int i = 0; i < 4; ++i) {
                int lg = p4 * 4 + i;
                *(uint4*)(h + (size_t)gr * 128 + lg * 8) = raw[i];
                unsigned short ob[8];
                for (int k = 0; k < 8; ++k) {
                    int col = lg * 8 + k;
                    ob[k] = f2bfbits((vals[i * 8 + k] - m) * rs * ln_g[col] + ln_b[col]);
                }
                uint4 o;
                o.x = ob[0] | ((unsigned)ob[1] << 16);
                o.y = ob[2] | ((unsigned)ob[3] << 16);
                o.z = ob[4] | ((unsigned)ob[5] << 16);
                o.w = ob[6] | ((unsigned)ob[7] << 16);
                *(uint4*)(xres + (size_t)gr * 128 + lg * 8) = o;
            }
        }
    }

    // ---- branches: alpha (relu/softplus), beta (relu/softplus), gamma (gelu/none)
    for (int br = 0; br < 3; ++br) {
        const bf16_t* w1 = wt + (1 + 2 * br) * 16384;
        const bf16_t* w2 = wt + (2 + 2 * br) * 16384;
        const float* b1p = (br == 0) ? ba1 : (br == 1) ? bb1 : bg1;
        const float* b2p = (br == 0) ? ba2 : (br == 1) ? bb2 : bg2;
        bf16_t* outp = (br == 0) ? al : (br == 1) ? be : ga;
        const int act1 = (br == 2) ? 2 : 1;
        const int act2 = (br == 2) ? 0 : 3;
        float b1_r[8], b2_r[8];
        for (int ni = 0; ni < 8; ++ni) {
            b1_r[ni] = b1p[ni * 16 + l15];
            b2_r[ni] = b2p[ni * 16 + l15];
        }

        load_w_regs(w1, wr, t);
        __syncthreads();                 // prior Csw/Bs readers done
        store_w_regs(wr, Bs, t);
        load_w_regs(w2, wr, t);          // prefetch second weight
        __syncthreads();                 // Bs(w1) ready

        kloop64(af_h, Bs, acc, l15, quad);
        __syncthreads();                 // done reading Bs; Csw free
        write_Csw(Csw, acc, b1_r, lane, wave, act1);
        store_w_regs(wr, Bs, t);
        __syncthreads();                 // Csw(t1) + Bs(w2) ready

        afrag_Csw(Csw, af, lane, wave);
        kloop64(af, Bs, acc, l15, quad);
        __syncthreads();                 // done reading Csw & Bs
        write_Csw(Csw, acc, b2_r, lane, wave, act2);
        __syncthreads();                 // Csw(out) ready
        copy_Csw_out(Csw, outp, t, r0, M);
    }
}

// ---------------------------------------------------------------------------
// Kernel C: z = gelu(y@Wf1+bf1)@Wf2 + bf2 + xres -> out fp32
// ---------------------------------------------------------------------------
__global__ __launch_bounds__(256, 3) void fused_out(
    const bf16_t* __restrict__ y, const bf16_t* __restrict__ wt,
    const float* __restrict__ bf1, const float* __restrict__ bf2,
    const bf16_t* __restrict__ xres, float* __restrict__ out, int M)
{
    __shared__ __align__(16) char smem[49152];
    bf16_t* Bs  = (bf16_t*)smem;
    bf16_t* Csw = (bf16_t*)(smem + 32768);
    float*  Cf  = (float*)smem;
    const int t = threadIdx.x;
    const int r0 = blockIdx.x * 64;
    const int lane = t & 63, wave = t >> 6, l15 = lane & 15, quad = lane >> 4;
    uint4 wr[8];
    bf16x8 af[4];
    floatx4 acc[8];

    float b1_r[8], b2_r[8];
    for (int ni = 0; ni < 8; ++ni) {
        b1_r[ni] = bf1[ni * 16 + l15];
        b2_r[ni] = bf2[ni * 16 + l15];
    }

    afrag_gbf16(y, af, r0, lane, wave, M);
    load_w_regs(wt + 7 * 16384, wr, t);
    store_w_regs(wr, Bs, t);
    load_w_regs(wt + 8 * 16384, wr, t);
    __syncthreads();

    kloop64(af, Bs, acc, l15, quad);
    __syncthreads();
    write_Csw(Csw, acc, b1_r, lane, wave, 2);   // gelu
    store_w_regs(wr, Bs, t);
    __syncthreads();

    afrag_Csw(Csw, af, lane, wave);
    kloop64(af, Bs, acc, l15, quad);
    __syncthreads();

    for (int ni = 0; ni < 8; ++ni) {
        int col = ni * 16 + l15;
        for (int r = 0; r < 4; ++r) {
            int row = wave * 16 + quad * 4 + r;
            Cf[row * 132 + col] = acc[ni][r] + b2_r[ni];
        }
    }
    __syncthreads();
    for (int i = 0; i < 8; ++i) {
        int c = t + i * 256;
        int row = c >> 5, q = c & 31;
        int gr = r0 + row;
        if (gr < M) {
            float4 v = *(const float4*)&Cf[row * 132 + q * 4];
            uint2 xr = *(const uint2*)(xres + (size_t)gr * 128 + q * 4);
            v.x += bfbits2f(xr.x << 16);
            v.y += bfbits2f(xr.x & 0xffff0000u);
            v.z += bfbits2f(xr.y << 16);
            v.w += bfbits2f(xr.y & 0xffff0000u);
            *(float4*)(out + (size_t)gr * 128 + q * 4) = v;
        }
    }
}

// ---------------------------------------------------------------------------
// Counting sort of edges by dst
// ---------------------------------------------------------------------------
__global__ __launch_bounds__(256) void hist_kernel(const int* __restrict__ ei,
                                                   int* __restrict__ cnt)
{
    int e = blockIdx.x * 256 + threadIdx.x;
    if (e < NEDGE) atomicAdd(&cnt[ei[NEDGE + e]], 1);
}

__global__ __launch_bounds__(256) void scan1_kernel(const int* __restrict__ cnt,
        int* __restrict__ offs, int* __restrict__ bsum)
{
    __shared__ int sd[256];
    int tid = threadIdx.x;
    int i = blockIdx.x * 256 + tid;
    int v = (i < NODES) ? cnt[i] : 0;
    sd[tid] = v;
    __syncthreads();
    for (int o = 1; o < 256; o <<= 1) {
        int other = (tid >= o) ? sd[tid - o] : 0;
        __syncthreads();
        sd[tid] += other;
        __syncthreads();
    }
    if (i < NODES) offs[i] = sd[tid] - v;
    if (tid == 255) bsum[blockIdx.x] = sd[255];
}

__global__ __launch_bounds__(256) void scan2_kernel(const int* __restrict__ bsum,
                                                    int* __restrict__ bofs)
{
    __shared__ int sd[256];
    int tid = threadIdx.x;
    int v = (tid < NBLK_SCAN) ? bsum[tid] : 0;
    sd[tid] = v;
    __syncthreads();
    for (int o = 1; o < 256; o <<= 1) {
        int other = (tid >= o) ? sd[tid - o] : 0;
        __syncthreads();
        sd[tid] += other;
        __syncthreads();
    }
    if (tid < NBLK_SCAN) bofs[tid] = sd[tid] - v;
}

__global__ __launch_bounds__(256) void scan3_kernel(const int* __restrict__ offs,
        const int* __restrict__ bofs, int* __restrict__ off_start,
        int* __restrict__ cur)
{
    int i = blockIdx.x * 256 + threadIdx.x;
    if (i < NODES) {
        int v = offs[i] + bofs[blockIdx.x];
        off_start[i] = v;
        cur[i] = v;
    }
}

__global__ __launch_bounds__(256) void reorder_kernel(const int* __restrict__ ei,
        int* __restrict__ cur, int* __restrict__ srcs)
{
    int e = blockIdx.x * 256 + threadIdx.x;
    if (e >= NEDGE) return;
    int dst = ei[NEDGE + e];
    int pos = atomicAdd(&cur[dst], 1);
    srcs[pos] = ei[e];
}

// ---------------------------------------------------------------------------
// Gather + y: one wave per node; quad-parallel 16B row loads
// ---------------------------------------------------------------------------
__global__ __launch_bounds__(256) void gather_y_kernel(
    const int* __restrict__ off_start, const int* __restrict__ cnt,
    const int* __restrict__ srcs, const bf16_t* __restrict__ h,
    const bf16_t* __restrict__ al, const bf16_t* __restrict__ be,
    const bf16_t* __restrict__ ga, const float* __restrict__ deg,
    bf16_t* __restrict__ y, int M)
{
    int wave = threadIdx.x >> 6, lane = threadIdx.x & 63;
    int node = blockIdx.x * 4 + wave;
    if (node >= M) return;
    int s0 = __builtin_amdgcn_readfirstlane(off_start[node]);
    int n  = __builtin_amdgcn_readfirstlane(cnt[node]);
    int grp = lane >> 4, c16 = lane & 15;
    float a[8] = {0.f, 0.f, 0.f, 0.f, 0.f, 0.f, 0.f, 0.f};

    for (int j = 0; j < n; j += 8) {
        int e0 = j + grp, e1 = j + 4 + grp;
        int i0 = srcs[s0 + min(e0, n - 1)];
        int i1 = srcs[s0 + min(e1, n - 1)];
        uint4 v0 = *(const uint4*)(h + (size_t)i0 * 128 + c16 * 8);
        uint4 v1 = *(const uint4*)(h + (size_t)i1 * 128 + c16 * 8);
        if (e0 < n) {
            const unsigned* u = (const unsigned*)&v0;
            for (int k = 0; k < 4; ++k) {
                a[2 * k]     += bfbits2f(u[k] << 16);
                a[2 * k + 1] += bfbits2f(u[k] & 0xffff0000u);
            }
        }
        if (e1 < n) {
            const unsigned* u = (const unsigned*)&v1;
            for (int k = 0; k < 4; ++k) {
                a[2 * k]     += bfbits2f(u[k] << 16);
                a[2 * k + 1] += bfbits2f(u[k] & 0xffff0000u);
            }
        }
    }
    for (int k = 0; k < 8; ++k) {
        a[k] += __shfl_xor(a[k], 16, 64);
        a[k] += __shfl_xor(a[k], 32, 64);
    }
    if (lane < 16) {
        size_t i0 = (size_t)node * 128 + (size_t)c16 * 8;
        uint4 ra = *(const uint4*)(al + i0);
        uint4 rb = *(const uint4*)(be + i0);
        uint4 rg = *(const uint4*)(ga + i0);
        float d = deg[node];
        const unsigned* ua = (const unsigned*)&ra;
        const unsigned* ub = (const unsigned*)&rb;
        const unsigned* ug = (const unsigned*)&rg;
        unsigned short o[8];
        for (int k = 0; k < 4; ++k) {
            float a0 = bfbits2f(ua[k] << 16), a1 = bfbits2f(ua[k] & 0xffff0000u);
            float b0 = bfbits2f(ub[k] << 16), b1 = bfbits2f(ub[k] & 0xffff0000u);
            float g0 = bfbits2f(ug[k] << 16), g1 = bfbits2f(ug[k] & 0xffff0000u);
            o[2 * k]     = f2bfbits((b0 * a[2 * k]     + g0) / (a0 + b0 * d));
            o[2 * k + 1] = f2bfbits((b1 * a[2 * k + 1] + g1) / (a1 + b1 * d));
        }
        uint4 ov;
        ov.x = o[0] | ((unsigned)o[1] << 16);
        ov.y = o[2] | ((unsigned)o[3] << 16);
        ov.z = o[4] | ((unsigned)o[5] << 16);
        ov.w = o[6] | ((unsigned)o[7] << 16);
        *(uint4*)(y + i0) = ov;
    }
}

// ---------------------------------------------------------------------------
extern "C" void kernel_launch(void* const* d_in, const int* in_sizes, int n_in,
                              void* d_out, int out_size, void* d_ws, size_t ws_size,
                              hipStream_t stream)
{
    const float* x    = (const float*)d_in[0];
    const int*   ei   = (const int*)d_in[1];
    const float* deg  = (const float*)d_in[2];
    const float* W_lin = (const float*)d_in[3];  const float* b_lin = (const float*)d_in[4];
    const float* Wa1 = (const float*)d_in[5];    const float* ba1 = (const float*)d_in[6];
    const float* Wa2 = (const float*)d_in[7];    const float* ba2 = (const float*)d_in[8];
    const float* Wb1 = (const float*)d_in[9];    const float* bb1 = (const float*)d_in[10];
    const float* Wb2 = (const float*)d_in[11];   const float* bb2 = (const float*)d_in[12];
    const float* Wg1 = (const float*)d_in[13];   const float* bg1 = (const float*)d_in[14];
    const float* Wg2 = (const float*)d_in[15];   const float* bg2 = (const float*)d_in[16];
    const float* Wf1 = (const float*)d_in[17];   const float* bf1 = (const float*)d_in[18];
    const float* Wf2 = (const float*)d_in[19];   const float* bf2 = (const float*)d_in[20];
    const float* ln_g = (const float*)d_in[21];  const float* ln_b = (const float*)d_in[22];

    const int M = NODES;
    const size_t NB2 = (size_t)M * 128 * 2;   // bf16 [N,128]

    char* ws = (char*)d_ws;
    size_t off = 0;
    bf16_t* wt  = (bf16_t*)(ws + off); off += (size_t)9 * 16384 * 2;
    bf16_t* h   = (bf16_t*)(ws + off); off += NB2;
    bf16_t* al  = (bf16_t*)(ws + off); off += NB2;
    bf16_t* be  = (bf16_t*)(ws + off); off += NB2;
    bf16_t* ga  = (bf16_t*)(ws + off); off += NB2;
    bf16_t* yv  = (bf16_t*)(ws + off); off += NB2;
    bf16_t* xres = (bf16_t*)(ws + off); off += NB2;
    int* cnt       = (int*)(ws + off); off += (size_t)NODES * 4 + 64;
    int* offs      = (int*)(ws + off); off += (size_t)NODES * 4 + 64;
    int* off_start = (int*)(ws + off); off += (size_t)NODES * 4 + 64;
    int* cur       = (int*)(ws + off); off += (size_t)NODES * 4 + 64;
    int* bsum      = (int*)(ws + off); off += 256 * 4;
    int* bofs      = (int*)(ws + off); off += 256 * 4;
    int* srcs      = (int*)(ws + off); off += (size_t)NEDGE * 4;
    float* outp = (float*)d_out;

    dim3 blk(256);
    int gT = (M + 63) / 64;               // 782 row-tiles
    int gE = (NEDGE + 255) / 256;         // 3125

    prep_weights<<<9, blk, 0, stream>>>(W_lin, Wa1, Wa2, Wb1, Wb2, Wg1, Wg2, Wf1, Wf2, wt);

    // counting sort of edges by dst
    hipMemsetAsync(cnt, 0, (size_t)NODES * 4, stream);
    hist_kernel<<<gE, blk, 0, stream>>>(ei, cnt);
    scan1_kernel<<<NBLK_SCAN, blk, 0, stream>>>(cnt, offs, bsum);
    scan2_kernel<<<1, blk, 0, stream>>>(bsum, bofs);
    scan3_kernel<<<NBLK_SCAN, blk, 0, stream>>>(offs, bofs, off_start, cur);
    // prime srcs into L2 so reorder's scattered 4B stores hit dirty lines
    hipMemsetAsync(srcs, 0, (size_t)NEDGE * 4, stream);
    reorder_kernel<<<gE, blk, 0, stream>>>(ei, cur, srcs);

    // fused: h, LN->xres, alpha, beta, gamma
    mlp_all<<<gT, blk, 0, stream>>>(x, wt, b_lin, ba1, ba2, bb1, bb2, bg1, bg2,
                                    ln_g, ln_b, h, xres, al, be, ga, M);
    // gather + y
    gather_y_kernel<<<(M + 3) / 4, blk, 0, stream>>>(off_start, cnt, srcs, h,
                                                     al, be, ga, deg, yv, M);
    // final MLP + residual
    fused_out<<<gT, blk, 0, stream>>>(yv, wt, bf1, bf2, xres, outp, M);
}

// Round 8
// 357.275 us; speedup vs baseline: 1.0490x; 1.0490x over previous
//
#include <hip/hip_runtime.h>
#include <hip/hip_bf16.h>
#include <math.h>

#define NODES 50000
#define NEDGE 800000
#define NBLK_SCAN ((NODES + 255) / 256)   // 196

typedef __bf16 bf16_t;
typedef __bf16 bf16x8 __attribute__((ext_vector_type(8)));
typedef float floatx4 __attribute__((ext_vector_type(4)));

__device__ __forceinline__ float bfbits2f(unsigned int hi16) {
    union { unsigned int u; float f; } c; c.u = hi16; return c.f;
}
__device__ __forceinline__ unsigned short f2bfbits(float f) {
    bf16_t b = (bf16_t)f; unsigned short u;
    __builtin_memcpy(&u, &b, 2); return u;
}

// act: 0=none, 1=relu, 2=gelu(tanh-approx, fast exp), 3=softplus(fast)
__device__ __forceinline__ float act_rt(float v, int act) {
    if (act == 1) return fmaxf(v, 0.f);
    if (act == 2) {
        float w = 0.79788456f * (v + 0.044715f * v * v * v);
        float e = __expf(2.f * w);
        float th = 1.f - 2.f / (e + 1.f);
        return 0.5f * v * (1.f + th);
    }
    if (act == 3) return fmaxf(v, 0.f) + __logf(1.f + __expf(-fabsf(v)));
    return v;
}

// ---------------------------------------------------------------------------
// Weight prep: 9 matrices W[k][n] fp32 -> Wt[n][k] bf16 (transposed)
// ---------------------------------------------------------------------------
__global__ __launch_bounds__(256) void prep_weights(
    const float* __restrict__ w0, const float* __restrict__ w1,
    const float* __restrict__ w2, const float* __restrict__ w3,
    const float* __restrict__ w4, const float* __restrict__ w5,
    const float* __restrict__ w6, const float* __restrict__ w7,
    const float* __restrict__ w8, bf16_t* __restrict__ wt)
{
    const float* Ws[9] = {w0, w1, w2, w3, w4, w5, w6, w7, w8};
    const float* W = Ws[blockIdx.x];
    bf16_t* o = wt + blockIdx.x * 16384;
    for (int idx = threadIdx.x; idx < 16384; idx += 256) {
        int k = idx >> 7, n = idx & 127;
        o[n * 128 + k] = (bf16_t)W[idx];
    }
}

// ---------------------------------------------------------------------------
// GEMM building blocks, 64-row tile structure (48 KB LDS -> 3 blocks/CU).
// Bs: 128x128 bf16 weight, XOR-swizzled. Csw: 64x128 bf16 bounce tile.
// ---------------------------------------------------------------------------
__device__ __forceinline__ void load_w_regs(const bf16_t* __restrict__ W,
                                            uint4 (&wr)[8], int t)
{
    for (int i = 0; i < 8; ++i) {
        int c = t + i * 256;
        int row = c >> 4, g = c & 15;
        wr[i] = *(const uint4*)(W + row * 128 + g * 8);
    }
}
__device__ __forceinline__ void store_w_regs(const uint4 (&wr)[8],
                                             bf16_t* Bs, int t)
{
    for (int i = 0; i < 8; ++i) {
        int c = t + i * 256;
        int row = c >> 4, g = c & 15;
        *(uint4*)&Bs[row * 128 + ((g ^ (row & 15)) * 8)] = wr[i];
    }
}
__device__ __forceinline__ void afrag_gbf16(const bf16_t* __restrict__ A,
        bf16x8 (&af)[4], int r0, int lane, int wave, int M)
{
    int gr = r0 + wave * 16 + (lane & 15);
    gr = min(gr, M - 1);
    const bf16_t* p = A + (size_t)gr * 128 + (lane >> 4) * 8;
    for (int kc = 0; kc < 4; ++kc)
        af[kc] = *(const bf16x8*)(p + kc * 32);
}
__device__ __forceinline__ void kloop64(const bf16x8 (&af)[4], const bf16_t* Bs,
                                        floatx4 (&acc)[8], int l15, int quad)
{
    for (int ni = 0; ni < 8; ++ni)
        for (int r = 0; r < 4; ++r) acc[ni][r] = 0.f;
    for (int kc = 0; kc < 4; ++kc) {
        int kg = kc * 4 + quad;
        bf16x8 b[8];
        for (int ni = 0; ni < 8; ++ni) {
            int row = ni * 16 + l15;
            b[ni] = *(const bf16x8*)&Bs[row * 128 + ((kg ^ l15) * 8)];
        }
        for (int ni = 0; ni < 8; ++ni)
            acc[ni] = __builtin_amdgcn_mfma_f32_16x16x32_bf16(
                af[kc], b[ni], acc[ni], 0, 0, 0);
    }
}
__device__ __forceinline__ void write_Csw(bf16_t* Csw, floatx4 (&acc)[8],
        const float (&bias_r)[8], int lane, int wave, int act)
{
    const int l15 = lane & 15, quad = lane >> 4;
    for (int ni = 0; ni < 8; ++ni) {
        int col = ni * 16 + l15;
        for (int r = 0; r < 4; ++r) {
            int row = wave * 16 + quad * 4 + r;
            float v = act_rt(acc[ni][r] + bias_r[ni], act);
            Csw[row * 128 + (((col >> 3) ^ (row & 15)) << 3) + (col & 7)] = (bf16_t)v;
        }
    }
}
__device__ __forceinline__ void afrag_Csw(const bf16_t* Csw, bf16x8 (&af)[4],
                                          int lane, int wave)
{
    int l15 = lane & 15, quad = lane >> 4;
    int row = wave * 16 + l15;
    for (int kc = 0; kc < 4; ++kc) {
        int kg = kc * 4 + quad;
        af[kc] = *(const bf16x8*)&Csw[row * 128 + ((kg ^ l15) * 8)];
    }
}
__device__ __forceinline__ void copy_Csw_out(const bf16_t* Csw,
        bf16_t* __restrict__ out, int t, int r0, int M)
{
    for (int i = 0; i < 4; ++i) {
        int c = t + i * 256;
        int row = c >> 4, g = c & 15;
        int gr = r0 + row;
        if (gr < M)
            *(uint4*)(out + (size_t)gr * 128 + g * 8) =
                *(const uint4*)&Csw[row * 128 + ((g ^ (row & 15)) * 8)];
    }
}

// ---------------------------------------------------------------------------
// Kernel A: h = x@W_lin + b_lin ; xres = LN(h).  64-row tiles, grid 782.
// (round-5 verified version)
// ---------------------------------------------------------------------------
__global__ __launch_bounds__(256, 3) void h_ln_kernel(
    const float* __restrict__ x, const bf16_t* __restrict__ wt,
    const float* __restrict__ b_lin,
    const float* __restrict__ ln_g, const float* __restrict__ ln_b,
    bf16_t* __restrict__ h, bf16_t* __restrict__ xres, int M)
{
    __shared__ __align__(16) char smem[49152];
    bf16_t* Bs  = (bf16_t*)smem;
    bf16_t* Csw = (bf16_t*)(smem + 32768);
    const int t = threadIdx.x;
    const int r0 = blockIdx.x * 64;
    const int lane = t & 63, wave = t >> 6, l15 = lane & 15, quad = lane >> 4;
    uint4 wr[8];
    bf16x8 af[4];
    floatx4 acc[8];
    float bias_r[8];
    for (int ni = 0; ni < 8; ++ni) bias_r[ni] = b_lin[ni * 16 + l15];

    // A-fragments straight from fp32 x
    {
        int gr = min(r0 + wave * 16 + l15, M - 1);
        const float* p = x + (size_t)gr * 128 + quad * 8;
        for (int kc = 0; kc < 4; ++kc) {
            float4 u0 = *(const float4*)(p + kc * 32);
            float4 u1 = *(const float4*)(p + kc * 32 + 4);
            bf16x8 f;
            f[0] = (bf16_t)u0.x; f[1] = (bf16_t)u0.y;
            f[2] = (bf16_t)u0.z; f[3] = (bf16_t)u0.w;
            f[4] = (bf16_t)u1.x; f[5] = (bf16_t)u1.y;
            f[6] = (bf16_t)u1.z; f[7] = (bf16_t)u1.w;
            af[kc] = f;
        }
    }
    load_w_regs(wt, wr, t);
    store_w_regs(wr, Bs, t);
    __syncthreads();
    kloop64(af, Bs, acc, l15, quad);
    write_Csw(Csw, acc, bias_r, lane, wave, 0);
    __syncthreads();

    // LN from Csw: 4 threads per row, 32 cols each; write h and xres
    int row = t >> 2, p4 = t & 3;
    int gr = r0 + row;
    uint4 raw[4];
    float vals[32];
    float s = 0.f, sq = 0.f;
    for (int i = 0; i < 4; ++i) {
        int lg = p4 * 4 + i;
        raw[i] = *(const uint4*)&Csw[row * 128 + ((lg ^ (row & 15)) * 8)];
        const unsigned* u = (const unsigned*)&raw[i];
        for (int k = 0; k < 4; ++k) {
            float f0 = bfbits2f(u[k] << 16);
            float f1 = bfbits2f(u[k] & 0xffff0000u);
            vals[i * 8 + k * 2] = f0; vals[i * 8 + k * 2 + 1] = f1;
            s += f0 + f1; sq += f0 * f0 + f1 * f1;
        }
    }
    s += __shfl_xor(s, 1, 64);  sq += __shfl_xor(sq, 1, 64);
    s += __shfl_xor(s, 2, 64);  sq += __shfl_xor(sq, 2, 64);
    float m   = s * (1.f / 128.f);
    float var = fmaxf(sq * (1.f / 128.f) - m * m, 0.f);
    float rs  = rsqrtf(var + 1e-5f);
    if (gr < M) {
        for (int i = 0; i < 4; ++i) {
            int lg = p4 * 4 + i;
            *(uint4*)(h + (size_t)gr * 128 + lg * 8) = raw[i];
            unsigned short ob[8];
            for (int k = 0; k < 8; ++k) {
                int col = lg * 8 + k;
                ob[k] = f2bfbits((vals[i * 8 + k] - m) * rs * ln_g[col] + ln_b[col]);
            }
            uint4 o;
            o.x = ob[0] | ((unsigned)ob[1] << 16);
            o.y = ob[2] | ((unsigned)ob[3] << 16);
            o.z = ob[4] | ((unsigned)ob[5] << 16);
            o.w = ob[6] | ((unsigned)ob[7] << 16);
            *(uint4*)(xres + (size_t)gr * 128 + lg * 8) = o;
        }
    }
}

// ---------------------------------------------------------------------------
// Kernel B: one block = one branch x one 64-row tile. grid = 3*782.
// ---------------------------------------------------------------------------
__global__ __launch_bounds__(256, 3) void branch_kernel(
    const bf16_t* __restrict__ h, const bf16_t* __restrict__ wt,
    const float* __restrict__ ba1, const float* __restrict__ ba2,
    const float* __restrict__ bb1, const float* __restrict__ bb2,
    const float* __restrict__ bg1, const float* __restrict__ bg2,
    bf16_t* __restrict__ al, bf16_t* __restrict__ be, bf16_t* __restrict__ ga,
    int M)
{
    __shared__ __align__(16) char smem[49152];
    bf16_t* Bs  = (bf16_t*)smem;
    bf16_t* Csw = (bf16_t*)(smem + 32768);
    const int t = threadIdx.x;
    const int nt = (M + 63) >> 6;            // tiles per branch (782)
    const int branch = blockIdx.x / nt;
    const int r0 = (blockIdx.x % nt) * 64;
    const int lane = t & 63, wave = t >> 6, l15 = lane & 15, quad = lane >> 4;
    uint4 wr[8];
    bf16x8 af[4];
    floatx4 acc[8];

    const bf16_t* w1 = wt + (1 + 2 * branch) * 16384;
    const bf16_t* w2 = wt + (2 + 2 * branch) * 16384;
    const float* b1p = (branch == 0) ? ba1 : (branch == 1) ? bb1 : bg1;
    const float* b2p = (branch == 0) ? ba2 : (branch == 1) ? bb2 : bg2;
    bf16_t* out = (branch == 0) ? al : (branch == 1) ? be : ga;
    const int act1 = (branch == 2) ? 2 : 1;
    const int act2 = (branch == 2) ? 0 : 3;

    float b1_r[8], b2_r[8];
    for (int ni = 0; ni < 8; ++ni) {
        b1_r[ni] = b1p[ni * 16 + l15];
        b2_r[ni] = b2p[ni * 16 + l15];
    }

    afrag_gbf16(h, af, r0, lane, wave, M);
    load_w_regs(w1, wr, t);
    store_w_regs(wr, Bs, t);
    load_w_regs(w2, wr, t);                  // prefetch second weight
    __syncthreads();

    kloop64(af, Bs, acc, l15, quad);
    write_Csw(Csw, acc, b1_r, lane, wave, act1);
    __syncthreads();
    store_w_regs(wr, Bs, t);                 // Bs <- W2
    __syncthreads();

    afrag_Csw(Csw, af, lane, wave);
    kloop64(af, Bs, acc, l15, quad);
    __syncthreads();
    write_Csw(Csw, acc, b2_r, lane, wave, act2);
    __syncthreads();
    copy_Csw_out(Csw, out, t, r0, M);
}

// ---------------------------------------------------------------------------
// Kernel C: z = gelu(y@Wf1+bf1)@Wf2 + bf2 + xres -> out fp32
// ---------------------------------------------------------------------------
__global__ __launch_bounds__(256, 3) void fused_out(
    const bf16_t* __restrict__ y, const bf16_t* __restrict__ wt,
    const float* __restrict__ bf1, const float* __restrict__ bf2,
    const bf16_t* __restrict__ xres, float* __restrict__ out, int M)
{
    __shared__ __align__(16) char smem[49152];
    bf16_t* Bs  = (bf16_t*)smem;
    bf16_t* Csw = (bf16_t*)(smem + 32768);
    float*  Cf  = (float*)smem;
    const int t = threadIdx.x;
    const int r0 = blockIdx.x * 64;
    const int lane = t & 63, wave = t >> 6, l15 = lane & 15, quad = lane >> 4;
    uint4 wr[8];
    bf16x8 af[4];
    floatx4 acc[8];

    float b1_r[8], b2_r[8];
    for (int ni = 0; ni < 8; ++ni) {
        b1_r[ni] = bf1[ni * 16 + l15];
        b2_r[ni] = bf2[ni * 16 + l15];
    }

    afrag_gbf16(y, af, r0, lane, wave, M);
    load_w_regs(wt + 7 * 16384, wr, t);
    store_w_regs(wr, Bs, t);
    load_w_regs(wt + 8 * 16384, wr, t);
    __syncthreads();

    kloop64(af, Bs, acc, l15, quad);
    write_Csw(Csw, acc, b1_r, lane, wave, 2);   // gelu
    __syncthreads();
    store_w_regs(wr, Bs, t);
    __syncthreads();

    afrag_Csw(Csw, af, lane, wave);
    kloop64(af, Bs, acc, l15, quad);
    __syncthreads();

    for (int ni = 0; ni < 8; ++ni) {
        int col = ni * 16 + l15;
        for (int r = 0; r < 4; ++r) {
            int row = wave * 16 + quad * 4 + r;
            Cf[row * 132 + col] = acc[ni][r] + b2_r[ni];
        }
    }
    __syncthreads();
    for (int i = 0; i < 8; ++i) {
        int c = t + i * 256;
        int row = c >> 5, q = c & 31;
        int gr = r0 + row;
        if (gr < M) {
            float4 v = *(const float4*)&Cf[row * 132 + q * 4];
            uint2 xr = *(const uint2*)(xres + (size_t)gr * 128 + q * 4);
            v.x += bfbits2f(xr.x << 16);
            v.y += bfbits2f(xr.x & 0xffff0000u);
            v.z += bfbits2f(xr.y << 16);
            v.w += bfbits2f(xr.y & 0xffff0000u);
            *(float4*)(out + (size_t)gr * 128 + q * 4) = v;
        }
    }
}

// ---------------------------------------------------------------------------
// Counting sort of edges by dst (round-5 verified version)
// ---------------------------------------------------------------------------
__global__ __launch_bounds__(256) void hist_kernel(const int* __restrict__ ei,
                                                   int* __restrict__ cnt)
{
    int e = blockIdx.x * 256 + threadIdx.x;
    if (e < NEDGE) atomicAdd(&cnt[ei[NEDGE + e]], 1);
}

__global__ __launch_bounds__(256) void scan1_kernel(const int* __restrict__ cnt,
        int* __restrict__ offs, int* __restrict__ bsum)
{
    __shared__ int sd[256];
    int tid = threadIdx.x;
    int i = blockIdx.x * 256 + tid;
    int v = (i < NODES) ? cnt[i] : 0;
    sd[tid] = v;
    __syncthreads();
    for (int o = 1; o < 256; o <<= 1) {
        int other = (tid >= o) ? sd[tid - o] : 0;
        __syncthreads();
        sd[tid] += other;
        __syncthreads();
    }
    if (i < NODES) offs[i] = sd[tid] - v;
    if (tid == 255) bsum[blockIdx.x] = sd[255];
}

__global__ __launch_bounds__(256) void scan2_kernel(const int* __restrict__ bsum,
                                                    int* __restrict__ bofs)
{
    __shared__ int sd[256];
    int tid = threadIdx.x;
    int v = (tid < NBLK_SCAN) ? bsum[tid] : 0;
    sd[tid] = v;
    __syncthreads();
    for (int o = 1; o < 256; o <<= 1) {
        int other = (tid >= o) ? sd[tid - o] : 0;
        __syncthreads();
        sd[tid] += other;
        __syncthreads();
    }
    if (tid < NBLK_SCAN) bofs[tid] = sd[tid] - v;
}

__global__ __launch_bounds__(256) void scan3_kernel(const int* __restrict__ offs,
        const int* __restrict__ bofs, int* __restrict__ off_start,
        int* __restrict__ cur)
{
    int i = blockIdx.x * 256 + threadIdx.x;
    if (i < NODES) {
        int v = offs[i] + bofs[blockIdx.x];
        off_start[i] = v;
        cur[i] = v;
    }
}

__global__ __launch_bounds__(256) void reorder_kernel(const int* __restrict__ ei,
        int* __restrict__ cur, int* __restrict__ srcs)
{
    int e = blockIdx.x * 256 + threadIdx.x;
    if (e >= NEDGE) return;
    int dst = ei[NEDGE + e];
    int pos = atomicAdd(&cur[dst], 1);
    // nontemporal: scattered 4B store, avoid L2 write-allocate amplification
    __builtin_nontemporal_store(ei[e], &srcs[pos]);
}

// ---------------------------------------------------------------------------
// Gather + y: one wave per node; quad-parallel 16B row loads
// ---------------------------------------------------------------------------
__global__ __launch_bounds__(256) void gather_y_kernel(
    const int* __restrict__ off_start, const int* __restrict__ cnt,
    const int* __restrict__ srcs, const bf16_t* __restrict__ h,
    const bf16_t* __restrict__ al, const bf16_t* __restrict__ be,
    const bf16_t* __restrict__ ga, const float* __restrict__ deg,
    bf16_t* __restrict__ y, int M)
{
    int wave = threadIdx.x >> 6, lane = threadIdx.x & 63;
    int node = blockIdx.x * 4 + wave;
    if (node >= M) return;
    int s0 = __builtin_amdgcn_readfirstlane(off_start[node]);
    int n  = __builtin_amdgcn_readfirstlane(cnt[node]);
    int grp = lane >> 4, c16 = lane & 15;
    float a[8] = {0.f, 0.f, 0.f, 0.f, 0.f, 0.f, 0.f, 0.f};

    for (int j = 0; j < n; j += 8) {
        int e0 = j + grp, e1 = j + 4 + grp;
        int i0 = srcs[s0 + min(e0, n - 1)];
        int i1 = srcs[s0 + min(e1, n - 1)];
        uint4 v0 = *(const uint4*)(h + (size_t)i0 * 128 + c16 * 8);
        uint4 v1 = *(const uint4*)(h + (size_t)i1 * 128 + c16 * 8);
        if (e0 < n) {
            const unsigned* u = (const unsigned*)&v0;
            for (int k = 0; k < 4; ++k) {
                a[2 * k]     += bfbits2f(u[k] << 16);
                a[2 * k + 1] += bfbits2f(u[k] & 0xffff0000u);
            }
        }
        if (e1 < n) {
            const unsigned* u = (const unsigned*)&v1;
            for (int k = 0; k < 4; ++k) {
                a[2 * k]     += bfbits2f(u[k] << 16);
                a[2 * k + 1] += bfbits2f(u[k] & 0xffff0000u);
            }
        }
    }
    for (int k = 0; k < 8; ++k) {
        a[k] += __shfl_xor(a[k], 16, 64);
        a[k] += __shfl_xor(a[k], 32, 64);
    }
    if (lane < 16) {
        size_t i0 = (size_t)node * 128 + (size_t)c16 * 8;
        uint4 ra = *(const uint4*)(al + i0);
        uint4 rb = *(const uint4*)(be + i0);
        uint4 rg = *(const uint4*)(ga + i0);
        float d = deg[node];
        const unsigned* ua = (const unsigned*)&ra;
        const unsigned* ub = (const unsigned*)&rb;
        const unsigned* ug = (const unsigned*)&rg;
        unsigned short o[8];
        for (int k = 0; k < 4; ++k) {
            float a0 = bfbits2f(ua[k] << 16), a1 = bfbits2f(ua[k] & 0xffff0000u);
            float b0 = bfbits2f(ub[k] << 16), b1 = bfbits2f(ub[k] & 0xffff0000u);
            float g0 = bfbits2f(ug[k] << 16), g1 = bfbits2f(ug[k] & 0xffff0000u);
            o[2 * k]     = f2bfbits((b0 * a[2 * k]     + g0) / (a0 + b0 * d));
            o[2 * k + 1] = f2bfbits((b1 * a[2 * k + 1] + g1) / (a1 + b1 * d));
        }
        uint4 ov;
        ov.x = o[0] | ((unsigned)o[1] << 16);
        ov.y = o[2] | ((unsigned)o[3] << 16);
        ov.z = o[4] | ((unsigned)o[5] << 16);
        ov.w = o[6] | ((unsigned)o[7] << 16);
        *(uint4*)(y + i0) = ov;
    }
}

// ---------------------------------------------------------------------------
extern "C" void kernel_launch(void* const* d_in, const int* in_sizes, int n_in,
                              void* d_out, int out_size, void* d_ws, size_t ws_size,
                              hipStream_t stream)
{
    const float* x    = (const float*)d_in[0];
    const int*   ei   = (const int*)d_in[1];
    const float* deg  = (const float*)d_in[2];
    const float* W_lin = (const float*)d_in[3];  const float* b_lin = (const float*)d_in[4];
    const float* Wa1 = (const float*)d_in[5];    const float* ba1 = (const float*)d_in[6];
    const float* Wa2 = (const float*)d_in[7];    const float* ba2 = (const float*)d_in[8];
    const float* Wb1 = (const float*)d_in[9];    const float* bb1 = (const float*)d_in[10];
    const float* Wb2 = (const float*)d_in[11];   const float* bb2 = (const float*)d_in[12];
    const float* Wg1 = (const float*)d_in[13];   const float* bg1 = (const float*)d_in[14];
    const float* Wg2 = (const float*)d_in[15];   const float* bg2 = (const float*)d_in[16];
    const float* Wf1 = (const float*)d_in[17];   const float* bf1 = (const float*)d_in[18];
    const float* Wf2 = (const float*)d_in[19];   const float* bf2 = (const float*)d_in[20];
    const float* ln_g = (const float*)d_in[21];  const float* ln_b = (const float*)d_in[22];

    const int M = NODES;
    const size_t NB2 = (size_t)M * 128 * 2;   // bf16 [N,128]

    char* ws = (char*)d_ws;
    size_t off = 0;
    bf16_t* wt  = (bf16_t*)(ws + off); off += (size_t)9 * 16384 * 2;
    bf16_t* h   = (bf16_t*)(ws + off); off += NB2;
    bf16_t* al  = (bf16_t*)(ws + off); off += NB2;
    bf16_t* be  = (bf16_t*)(ws + off); off += NB2;
    bf16_t* ga  = (bf16_t*)(ws + off); off += NB2;
    bf16_t* yv  = (bf16_t*)(ws + off); off += NB2;
    bf16_t* xres = (bf16_t*)(ws + off); off += NB2;
    int* cnt       = (int*)(ws + off); off += (size_t)NODES * 4 + 64;
    int* offs      = (int*)(ws + off); off += (size_t)NODES * 4 + 64;
    int* off_start = (int*)(ws + off); off += (size_t)NODES * 4 + 64;
    int* cur       = (int*)(ws + off); off += (size_t)NODES * 4 + 64;
    int* bsum      = (int*)(ws + off); off += 256 * 4;
    int* bofs      = (int*)(ws + off); off += 256 * 4;
    int* srcs      = (int*)(ws + off); off += (size_t)NEDGE * 4;
    float* outp = (float*)d_out;

    dim3 blk(256);
    int gT = (M + 63) / 64;               // 782 row-tiles
    int gE = (NEDGE + 255) / 256;         // 3125

    prep_weights<<<9, blk, 0, stream>>>(W_lin, Wa1, Wa2, Wb1, Wb2, Wg1, Wg2, Wf1, Wf2, wt);

    // counting sort of edges by dst
    hipMemsetAsync(cnt, 0, (size_t)NODES * 4, stream);
    hist_kernel<<<gE, blk, 0, stream>>>(ei, cnt);
    scan1_kernel<<<NBLK_SCAN, blk, 0, stream>>>(cnt, offs, bsum);
    scan2_kernel<<<1, blk, 0, stream>>>(bsum, bofs);
    scan3_kernel<<<NBLK_SCAN, blk, 0, stream>>>(offs, bofs, off_start, cur);
    reorder_kernel<<<gE, blk, 0, stream>>>(ei, cur, srcs);

    // h = x@W_lin + b_lin ; xres = LN(h)
    h_ln_kernel<<<gT, blk, 0, stream>>>(x, wt, b_lin, ln_g, ln_b, h, xres, M);
    // alpha / beta / gamma: 3 branches x 782 tiles
    branch_kernel<<<3 * gT, blk, 0, stream>>>(h, wt, ba1, ba2, bb1, bb2, bg1, bg2,
                                              al, be, ga, M);
    // gather + y
    gather_y_kernel<<<(M + 3) / 4, blk, 0, stream>>>(off_start, cnt, srcs, h,
                                                     al, be, ga, deg, yv, M);
    // final MLP + residual
    fused_out<<<gT, blk, 0, stream>>>(yv, wt, bf1, bf2, xres, outp, M);
}

// Round 9
// 305.496 us; speedup vs baseline: 1.2268x; 1.1695x over previous
//
#include <hip/hip_runtime.h>
#include <hip/hip_bf16.h>
#include <math.h>

#define NODES 50000
#define NEDGE 800000
#define NBLK_SCAN ((NODES + 255) / 256)   // 196
#define NT_TILES 782                      // 64-row tiles
#define NR_BLK 1563                       // reorder blocks (x512 edges)

typedef __bf16 bf16_t;
typedef __bf16 bf16x8 __attribute__((ext_vector_type(8)));
typedef float floatx4 __attribute__((ext_vector_type(4)));

__device__ __forceinline__ float bfbits2f(unsigned int hi16) {
    union { unsigned int u; float f; } c; c.u = hi16; return c.f;
}
__device__ __forceinline__ unsigned short f2bfbits(float f) {
    bf16_t b = (bf16_t)f; unsigned short u;
    __builtin_memcpy(&u, &b, 2); return u;
}

// act: 0=none, 1=relu, 2=gelu(tanh-approx, fast exp), 3=softplus(fast)
__device__ __forceinline__ float act_rt(float v, int act) {
    if (act == 1) return fmaxf(v, 0.f);
    if (act == 2) {
        float w = 0.79788456f * (v + 0.044715f * v * v * v);
        float e = __expf(2.f * w);
        float th = 1.f - 2.f / (e + 1.f);
        return 0.5f * v * (1.f + th);
    }
    if (act == 3) return fmaxf(v, 0.f) + __logf(1.f + __expf(-fabsf(v)));
    return v;
}

// ---------------------------------------------------------------------------
// prep: blocks 0..8 transpose weights fp32->bf16; blocks 9..204 zero cnt
// ---------------------------------------------------------------------------
__global__ __launch_bounds__(256) void prep_w_zero(
    const float* __restrict__ w0, const float* __restrict__ w1,
    const float* __restrict__ w2, const float* __restrict__ w3,
    const float* __restrict__ w4, const float* __restrict__ w5,
    const float* __restrict__ w6, const float* __restrict__ w7,
    const float* __restrict__ w8, bf16_t* __restrict__ wt,
    int* __restrict__ cnt)
{
    if (blockIdx.x >= 9) {
        int i = (blockIdx.x - 9) * 256 + threadIdx.x;
        if (i < NODES) cnt[i] = 0;
        return;
    }
    const float* Ws[9] = {w0, w1, w2, w3, w4, w5, w6, w7, w8};
    const float* W = Ws[blockIdx.x];
    bf16_t* o = wt + blockIdx.x * 16384;
    for (int idx = threadIdx.x; idx < 16384; idx += 256) {
        int k = idx >> 7, n = idx & 127;
        o[n * 128 + k] = (bf16_t)W[idx];
    }
}

// ---------------------------------------------------------------------------
// GEMM building blocks, 64-row tile structure (48 KB LDS -> 3 blocks/CU).
// ---------------------------------------------------------------------------
__device__ __forceinline__ void load_w_regs(const bf16_t* __restrict__ W,
                                            uint4 (&wr)[8], int t)
{
    for (int i = 0; i < 8; ++i) {
        int c = t + i * 256;
        int row = c >> 4, g = c & 15;
        wr[i] = *(const uint4*)(W + row * 128 + g * 8);
    }
}
__device__ __forceinline__ void store_w_regs(const uint4 (&wr)[8],
                                             bf16_t* Bs, int t)
{
    for (int i = 0; i < 8; ++i) {
        int c = t + i * 256;
        int row = c >> 4, g = c & 15;
        *(uint4*)&Bs[row * 128 + ((g ^ (row & 15)) * 8)] = wr[i];
    }
}
__device__ __forceinline__ void afrag_gbf16(const bf16_t* __restrict__ A,
        bf16x8 (&af)[4], int r0, int lane, int wave, int M)
{
    int gr = r0 + wave * 16 + (lane & 15);
    gr = min(gr, M - 1);
    const bf16_t* p = A + (size_t)gr * 128 + (lane >> 4) * 8;
    for (int kc = 0; kc < 4; ++kc)
        af[kc] = *(const bf16x8*)(p + kc * 32);
}
__device__ __forceinline__ void kloop64(const bf16x8 (&af)[4], const bf16_t* Bs,
                                        floatx4 (&acc)[8], int l15, int quad)
{
    for (int ni = 0; ni < 8; ++ni)
        for (int r = 0; r < 4; ++r) acc[ni][r] = 0.f;
    for (int kc = 0; kc < 4; ++kc) {
        int kg = kc * 4 + quad;
        bf16x8 b[8];
        for (int ni = 0; ni < 8; ++ni) {
            int row = ni * 16 + l15;
            b[ni] = *(const bf16x8*)&Bs[row * 128 + ((kg ^ l15) * 8)];
        }
        for (int ni = 0; ni < 8; ++ni)
            acc[ni] = __builtin_amdgcn_mfma_f32_16x16x32_bf16(
                af[kc], b[ni], acc[ni], 0, 0, 0);
    }
}
__device__ __forceinline__ void write_Csw(bf16_t* Csw, floatx4 (&acc)[8],
        const float (&bias_r)[8], int lane, int wave, int act)
{
    const int l15 = lane & 15, quad = lane >> 4;
    for (int ni = 0; ni < 8; ++ni) {
        int col = ni * 16 + l15;
        for (int r = 0; r < 4; ++r) {
            int row = wave * 16 + quad * 4 + r;
            float v = act_rt(acc[ni][r] + bias_r[ni], act);
            Csw[row * 128 + (((col >> 3) ^ (row & 15)) << 3) + (col & 7)] = (bf16_t)v;
        }
    }
}
__device__ __forceinline__ void afrag_Csw(const bf16_t* Csw, bf16x8 (&af)[4],
                                          int lane, int wave)
{
    int l15 = lane & 15, quad = lane >> 4;
    int row = wave * 16 + l15;
    for (int kc = 0; kc < 4; ++kc) {
        int kg = kc * 4 + quad;
        af[kc] = *(const bf16x8*)&Csw[row * 128 + ((kg ^ l15) * 8)];
    }
}
__device__ __forceinline__ void copy_Csw_out(const bf16_t* Csw,
        bf16_t* __restrict__ out, int t, int r0, int M)
{
    for (int i = 0; i < 4; ++i) {
        int c = t + i * 256;
        int row = c >> 4, g = c & 15;
        int gr = r0 + row;
        if (gr < M)
            *(uint4*)(out + (size_t)gr * 128 + g * 8) =
                *(const uint4*)&Csw[row * 128 + ((g ^ (row & 15)) * 8)];
    }
}

// ---------------------------------------------------------------------------
// hln_hist: even blocks run h_ln tile (g = bid>>1), odd blocks histogram
// 1024 edges each. Independent work co-scheduled in one dispatch.
// ---------------------------------------------------------------------------
__global__ __launch_bounds__(256, 3) void hln_hist(
    const float* __restrict__ x, const bf16_t* __restrict__ wt,
    const float* __restrict__ b_lin,
    const float* __restrict__ ln_g, const float* __restrict__ ln_b,
    bf16_t* __restrict__ h, bf16_t* __restrict__ xres,
    const int* __restrict__ ei, int* __restrict__ cnt, int M)
{
    __shared__ __align__(16) char smem[49152];
    const int t = threadIdx.x;
    const int g = blockIdx.x >> 1;

    if (blockIdx.x & 1) {
        // histogram part: 1024 edges
        int base = g * 1024;
        for (int i = 0; i < 4; ++i) {
            int e = base + i * 256 + t;
            if (e < NEDGE) atomicAdd(&cnt[ei[NEDGE + e]], 1);
        }
        return;
    }

    bf16_t* Bs  = (bf16_t*)smem;
    bf16_t* Csw = (bf16_t*)(smem + 32768);
    const int r0 = g * 64;
    const int lane = t & 63, wave = t >> 6, l15 = lane & 15, quad = lane >> 4;
    uint4 wr[8];
    bf16x8 af[4];
    floatx4 acc[8];
    float bias_r[8];
    for (int ni = 0; ni < 8; ++ni) bias_r[ni] = b_lin[ni * 16 + l15];

    {
        int gr = min(r0 + wave * 16 + l15, M - 1);
        const float* p = x + (size_t)gr * 128 + quad * 8;
        for (int kc = 0; kc < 4; ++kc) {
            float4 u0 = *(const float4*)(p + kc * 32);
            float4 u1 = *(const float4*)(p + kc * 32 + 4);
            bf16x8 f;
            f[0] = (bf16_t)u0.x; f[1] = (bf16_t)u0.y;
            f[2] = (bf16_t)u0.z; f[3] = (bf16_t)u0.w;
            f[4] = (bf16_t)u1.x; f[5] = (bf16_t)u1.y;
            f[6] = (bf16_t)u1.z; f[7] = (bf16_t)u1.w;
            af[kc] = f;
        }
    }
    load_w_regs(wt, wr, t);
    store_w_regs(wr, Bs, t);
    __syncthreads();
    kloop64(af, Bs, acc, l15, quad);
    write_Csw(Csw, acc, bias_r, lane, wave, 0);
    __syncthreads();

    int row = t >> 2, p4 = t & 3;
    int gr = r0 + row;
    uint4 raw[4];
    float vals[32];
    float s = 0.f, sq = 0.f;
    for (int i = 0; i < 4; ++i) {
        int lg = p4 * 4 + i;
        raw[i] = *(const uint4*)&Csw[row * 128 + ((lg ^ (row & 15)) * 8)];
        const unsigned* u = (const unsigned*)&raw[i];
        for (int k = 0; k < 4; ++k) {
            float f0 = bfbits2f(u[k] << 16);
            float f1 = bfbits2f(u[k] & 0xffff0000u);
            vals[i * 8 + k * 2] = f0; vals[i * 8 + k * 2 + 1] = f1;
            s += f0 + f1; sq += f0 * f0 + f1 * f1;
        }
    }
    s += __shfl_xor(s, 1, 64);  sq += __shfl_xor(sq, 1, 64);
    s += __shfl_xor(s, 2, 64);  sq += __shfl_xor(sq, 2, 64);
    float m   = s * (1.f / 128.f);
    float var = fmaxf(sq * (1.f / 128.f) - m * m, 0.f);
    float rs  = rsqrtf(var + 1e-5f);
    if (gr < M) {
        for (int i = 0; i < 4; ++i) {
            int lg = p4 * 4 + i;
            *(uint4*)(h + (size_t)gr * 128 + lg * 8) = raw[i];
            unsigned short ob[8];
            for (int k = 0; k < 8; ++k) {
                int col = lg * 8 + k;
                ob[k] = f2bfbits((vals[i * 8 + k] - m) * rs * ln_g[col] + ln_b[col]);
            }
            uint4 o;
            o.x = ob[0] | ((unsigned)ob[1] << 16);
            o.y = ob[2] | ((unsigned)ob[3] << 16);
            o.z = ob[4] | ((unsigned)ob[5] << 16);
            o.w = ob[6] | ((unsigned)ob[7] << 16);
            *(uint4*)(xres + (size_t)gr * 128 + lg * 8) = o;
        }
    }
}

// ---------------------------------------------------------------------------
// branch_reorder: groups of 5 blocks = 3 branch tiles + 2 reorder blocks
// (512 edges each). Independent work co-scheduled.
// ---------------------------------------------------------------------------
__global__ __launch_bounds__(256, 3) void branch_reorder(
    const bf16_t* __restrict__ h, const bf16_t* __restrict__ wt,
    const float* __restrict__ ba1, const float* __restrict__ ba2,
    const float* __restrict__ bb1, const float* __restrict__ bb2,
    const float* __restrict__ bg1, const float* __restrict__ bg2,
    bf16_t* __restrict__ al, bf16_t* __restrict__ be, bf16_t* __restrict__ ga,
    const int* __restrict__ ei, int* __restrict__ cur, int* __restrict__ srcs,
    int M)
{
    __shared__ __align__(16) char smem[49152];
    const int t = threadIdx.x;
    const int g5 = blockIdx.x / 5, r5 = blockIdx.x % 5;

    if (r5 >= 3) {
        // reorder part: 512 edges
        int rb = g5 * 2 + (r5 - 3);
        int base = rb * 512;
        for (int i = 0; i < 2; ++i) {
            int e = base + i * 256 + t;
            if (e < NEDGE) {
                int dst = ei[NEDGE + e];
                int pos = atomicAdd(&cur[dst], 1);
                srcs[pos] = ei[e];
            }
        }
        return;
    }

    bf16_t* Bs  = (bf16_t*)smem;
    bf16_t* Csw = (bf16_t*)(smem + 32768);
    const int bb = g5 * 3 + r5;              // branch-tile index 0..2345
    const int branch = bb / NT_TILES;
    const int r0 = (bb % NT_TILES) * 64;
    const int lane = t & 63, wave = t >> 6, l15 = lane & 15, quad = lane >> 4;
    uint4 wr[8];
    bf16x8 af[4];
    floatx4 acc[8];

    const bf16_t* w1 = wt + (1 + 2 * branch) * 16384;
    const bf16_t* w2 = wt + (2 + 2 * branch) * 16384;
    const float* b1p = (branch == 0) ? ba1 : (branch == 1) ? bb1 : bg1;
    const float* b2p = (branch == 0) ? ba2 : (branch == 1) ? bb2 : bg2;
    bf16_t* out = (branch == 0) ? al : (branch == 1) ? be : ga;
    const int act1 = (branch == 2) ? 2 : 1;
    const int act2 = (branch == 2) ? 0 : 3;

    float b1_r[8], b2_r[8];
    for (int ni = 0; ni < 8; ++ni) {
        b1_r[ni] = b1p[ni * 16 + l15];
        b2_r[ni] = b2p[ni * 16 + l15];
    }

    afrag_gbf16(h, af, r0, lane, wave, M);
    load_w_regs(w1, wr, t);
    store_w_regs(wr, Bs, t);
    load_w_regs(w2, wr, t);                  // prefetch second weight
    __syncthreads();

    kloop64(af, Bs, acc, l15, quad);
    write_Csw(Csw, acc, b1_r, lane, wave, act1);
    __syncthreads();
    store_w_regs(wr, Bs, t);                 // Bs <- W2
    __syncthreads();

    afrag_Csw(Csw, af, lane, wave);
    kloop64(af, Bs, acc, l15, quad);
    __syncthreads();
    write_Csw(Csw, acc, b2_r, lane, wave, act2);
    __syncthreads();
    copy_Csw_out(Csw, out, t, r0, M);
}

// ---------------------------------------------------------------------------
// Kernel C: z = gelu(y@Wf1+bf1)@Wf2 + bf2 + xres -> out fp32
// ---------------------------------------------------------------------------
__global__ __launch_bounds__(256, 3) void fused_out(
    const bf16_t* __restrict__ y, const bf16_t* __restrict__ wt,
    const float* __restrict__ bf1, const float* __restrict__ bf2,
    const bf16_t* __restrict__ xres, float* __restrict__ out, int M)
{
    __shared__ __align__(16) char smem[49152];
    bf16_t* Bs  = (bf16_t*)smem;
    bf16_t* Csw = (bf16_t*)(smem + 32768);
    float*  Cf  = (float*)smem;
    const int t = threadIdx.x;
    const int r0 = blockIdx.x * 64;
    const int lane = t & 63, wave = t >> 6, l15 = lane & 15, quad = lane >> 4;
    uint4 wr[8];
    bf16x8 af[4];
    floatx4 acc[8];

    float b1_r[8], b2_r[8];
    for (int ni = 0; ni < 8; ++ni) {
        b1_r[ni] = bf1[ni * 16 + l15];
        b2_r[ni] = bf2[ni * 16 + l15];
    }

    afrag_gbf16(y, af, r0, lane, wave, M);
    load_w_regs(wt + 7 * 16384, wr, t);
    store_w_regs(wr, Bs, t);
    load_w_regs(wt + 8 * 16384, wr, t);
    __syncthreads();

    kloop64(af, Bs, acc, l15, quad);
    write_Csw(Csw, acc, b1_r, lane, wave, 2);   // gelu
    __syncthreads();
    store_w_regs(wr, Bs, t);
    __syncthreads();

    afrag_Csw(Csw, af, lane, wave);
    kloop64(af, Bs, acc, l15, quad);
    __syncthreads();

    for (int ni = 0; ni < 8; ++ni) {
        int col = ni * 16 + l15;
        for (int r = 0; r < 4; ++r) {
            int row = wave * 16 + quad * 4 + r;
            Cf[row * 132 + col] = acc[ni][r] + b2_r[ni];
        }
    }
    __syncthreads();
    for (int i = 0; i < 8; ++i) {
        int c = t + i * 256;
        int row = c >> 5, q = c & 31;
        int gr = r0 + row;
        if (gr < M) {
            float4 v = *(const float4*)&Cf[row * 132 + q * 4];
            uint2 xr = *(const uint2*)(xres + (size_t)gr * 128 + q * 4);
            v.x += bfbits2f(xr.x << 16);
            v.y += bfbits2f(xr.x & 0xffff0000u);
            v.z += bfbits2f(xr.y << 16);
            v.w += bfbits2f(xr.y & 0xffff0000u);
            *(float4*)(out + (size_t)gr * 128 + q * 4) = v;
        }
    }
}

// ---------------------------------------------------------------------------
// scans
// ---------------------------------------------------------------------------
__global__ __launch_bounds__(256) void scan1_kernel(const int* __restrict__ cnt,
        int* __restrict__ offs, int* __restrict__ bsum)
{
    __shared__ int sd[256];
    int tid = threadIdx.x;
    int i = blockIdx.x * 256 + tid;
    int v = (i < NODES) ? cnt[i] : 0;
    sd[tid] = v;
    __syncthreads();
    for (int o = 1; o < 256; o <<= 1) {
        int other = (tid >= o) ? sd[tid - o] : 0;
        __syncthreads();
        sd[tid] += other;
        __syncthreads();
    }
    if (i < NODES) offs[i] = sd[tid] - v;
    if (tid == 255) bsum[blockIdx.x] = sd[255];
}

__global__ __launch_bounds__(256) void scan2_kernel(const int* __restrict__ bsum,
                                                    int* __restrict__ bofs)
{
    __shared__ int sd[256];
    int tid = threadIdx.x;
    int v = (tid < NBLK_SCAN) ? bsum[tid] : 0;
    sd[tid] = v;
    __syncthreads();
    for (int o = 1; o < 256; o <<= 1) {
        int other = (tid >= o) ? sd[tid - o] : 0;
        __syncthreads();
        sd[tid] += other;
        __syncthreads();
    }
    if (tid < NBLK_SCAN) bofs[tid] = sd[tid] - v;
}

__global__ __launch_bounds__(256) void scan3_kernel(const int* __restrict__ offs,
        const int* __restrict__ bofs, int* __restrict__ off_start,
        int* __restrict__ cur)
{
    int i = blockIdx.x * 256 + threadIdx.x;
    if (i < NODES) {
        int v = offs[i] + bofs[blockIdx.x];
        off_start[i] = v;
        cur[i] = v;
    }
}

// ---------------------------------------------------------------------------
// Gather + y: one wave per node; quad-parallel 16B row loads
// ---------------------------------------------------------------------------
__global__ __launch_bounds__(256) void gather_y_kernel(
    const int* __restrict__ off_start, const int* __restrict__ cnt,
    const int* __restrict__ srcs, const bf16_t* __restrict__ h,
    const bf16_t* __restrict__ al, const bf16_t* __restrict__ be,
    const bf16_t* __restrict__ ga, const float* __restrict__ deg,
    bf16_t* __restrict__ y, int M)
{
    int wave = threadIdx.x >> 6, lane = threadIdx.x & 63;
    int node = blockIdx.x * 4 + wave;
    if (node >= M) return;
    int s0 = __builtin_amdgcn_readfirstlane(off_start[node]);
    int n  = __builtin_amdgcn_readfirstlane(cnt[node]);
    int grp = lane >> 4, c16 = lane & 15;
    float a[8] = {0.f, 0.f, 0.f, 0.f, 0.f, 0.f, 0.f, 0.f};

    for (int j = 0; j < n; j += 8) {
        int e0 = j + grp, e1 = j + 4 + grp;
        int i0 = srcs[s0 + min(e0, n - 1)];
        int i1 = srcs[s0 + min(e1, n - 1)];
        uint4 v0 = *(const uint4*)(h + (size_t)i0 * 128 + c16 * 8);
        uint4 v1 = *(const uint4*)(h + (size_t)i1 * 128 + c16 * 8);
        if (e0 < n) {
            const unsigned* u = (const unsigned*)&v0;
            for (int k = 0; k < 4; ++k) {
                a[2 * k]     += bfbits2f(u[k] << 16);
                a[2 * k + 1] += bfbits2f(u[k] & 0xffff0000u);
            }
        }
        if (e1 < n) {
            const unsigned* u = (const unsigned*)&v1;
            for (int k = 0; k < 4; ++k) {
                a[2 * k]     += bfbits2f(u[k] << 16);
                a[2 * k + 1] += bfbits2f(u[k] & 0xffff0000u);
            }
        }
    }
    for (int k = 0; k < 8; ++k) {
        a[k] += __shfl_xor(a[k], 16, 64);
        a[k] += __shfl_xor(a[k], 32, 64);
    }
    if (lane < 16) {
        size_t i0 = (size_t)node * 128 + (size_t)c16 * 8;
        uint4 ra = *(const uint4*)(al + i0);
        uint4 rb = *(const uint4*)(be + i0);
        uint4 rg = *(const uint4*)(ga + i0);
        float d = deg[node];
        const unsigned* ua = (const unsigned*)&ra;
        const unsigned* ub = (const unsigned*)&rb;
        const unsigned* ug = (const unsigned*)&rg;
        unsigned short o[8];
        for (int k = 0; k < 4; ++k) {
            float a0 = bfbits2f(ua[k] << 16), a1 = bfbits2f(ua[k] & 0xffff0000u);
            float b0 = bfbits2f(ub[k] << 16), b1 = bfbits2f(ub[k] & 0xffff0000u);
            float g0 = bfbits2f(ug[k] << 16), g1 = bfbits2f(ug[k] & 0xffff0000u);
            o[2 * k]     = f2bfbits((b0 * a[2 * k]     + g0) / (a0 + b0 * d));
            o[2 * k + 1] = f2bfbits((b1 * a[2 * k + 1] + g1) / (a1 + b1 * d));
        }
        uint4 ov;
        ov.x = o[0] | ((unsigned)o[1] << 16);
        ov.y = o[2] | ((unsigned)o[3] << 16);
        ov.z = o[4] | ((unsigned)o[5] << 16);
        ov.w = o[6] | ((unsigned)o[7] << 16);
        *(uint4*)(y + i0) = ov;
    }
}

// ---------------------------------------------------------------------------
extern "C" void kernel_launch(void* const* d_in, const int* in_sizes, int n_in,
                              void* d_out, int out_size, void* d_ws, size_t ws_size,
                              hipStream_t stream)
{
    const float* x    = (const float*)d_in[0];
    const int*   ei   = (const int*)d_in[1];
    const float* deg  = (const float*)d_in[2];
    const float* W_lin = (const float*)d_in[3];  const float* b_lin = (const float*)d_in[4];
    const float* Wa1 = (const float*)d_in[5];    const float* ba1 = (const float*)d_in[6];
    const float* Wa2 = (const float*)d_in[7];    const float* ba2 = (const float*)d_in[8];
    const float* Wb1 = (const float*)d_in[9];    const float* bb1 = (const float*)d_in[10];
    const float* Wb2 = (const float*)d_in[11];   const float* bb2 = (const float*)d_in[12];
    const float* Wg1 = (const float*)d_in[13];   const float* bg1 = (const float*)d_in[14];
    const float* Wg2 = (const float*)d_in[15];   const float* bg2 = (const float*)d_in[16];
    const float* Wf1 = (const float*)d_in[17];   const float* bf1 = (const float*)d_in[18];
    const float* Wf2 = (const float*)d_in[19];   const float* bf2 = (const float*)d_in[20];
    const float* ln_g = (const float*)d_in[21];  const float* ln_b = (const float*)d_in[22];

    const int M = NODES;
    const size_t NB2 = (size_t)M * 128 * 2;   // bf16 [N,128]

    char* ws = (char*)d_ws;
    size_t off = 0;
    bf16_t* wt  = (bf16_t*)(ws + off); off += (size_t)9 * 16384 * 2;
    bf16_t* h   = (bf16_t*)(ws + off); off += NB2;
    bf16_t* al  = (bf16_t*)(ws + off); off += NB2;
    bf16_t* be  = (bf16_t*)(ws + off); off += NB2;
    bf16_t* ga  = (bf16_t*)(ws + off); off += NB2;
    bf16_t* yv  = (bf16_t*)(ws + off); off += NB2;
    bf16_t* xres = (bf16_t*)(ws + off); off += NB2;
    int* cnt       = (int*)(ws + off); off += (size_t)NODES * 4 + 64;
    int* offs      = (int*)(ws + off); off += (size_t)NODES * 4 + 64;
    int* off_start = (int*)(ws + off); off += (size_t)NODES * 4 + 64;
    int* cur       = (int*)(ws + off); off += (size_t)NODES * 4 + 64;
    int* bsum      = (int*)(ws + off); off += 256 * 4;
    int* bofs      = (int*)(ws + off); off += 256 * 4;
    int* srcs      = (int*)(ws + off); off += (size_t)NEDGE * 4;
    float* outp = (float*)d_out;

    dim3 blk(256);

    // weights transpose + cnt zero (one dispatch)
    prep_w_zero<<<9 + NBLK_SCAN, blk, 0, stream>>>(
        W_lin, Wa1, Wa2, Wb1, Wb2, Wg1, Wg2, Wf1, Wf2, wt, cnt);

    // h/LN co-launched with edge histogram (independent)
    hln_hist<<<2 * NT_TILES, blk, 0, stream>>>(
        x, wt, b_lin, ln_g, ln_b, h, xres, ei, cnt, M);

    // exclusive scan over cnt
    scan1_kernel<<<NBLK_SCAN, blk, 0, stream>>>(cnt, offs, bsum);
    scan2_kernel<<<1, blk, 0, stream>>>(bsum, bofs);
    scan3_kernel<<<NBLK_SCAN, blk, 0, stream>>>(offs, bofs, off_start, cur);

    // branches co-launched with edge reorder (independent)
    branch_reorder<<<5 * NT_TILES, blk, 0, stream>>>(
        h, wt, ba1, ba2, bb1, bb2, bg1, bg2, al, be, ga, ei, cur, srcs, M);

    // gather + y
    gather_y_kernel<<<(M + 3) / 4, blk, 0, stream>>>(off_start, cnt, srcs, h,
                                                     al, be, ga, deg, yv, M);
    // final MLP + residual
    fused_out<<<NT_TILES, blk, 0, stream>>>(yv, wt, bf1, bf2, xres, outp, M);
}

// Round 10
// 282.194 us; speedup vs baseline: 1.3281x; 1.0826x over previous
//
#include <hip/hip_runtime.h>
#include <hip/hip_bf16.h>
#include <math.h>

#define NODES 50000
#define NEDGE 800000
#define NT_TILES 782        // 64-row tiles
#define NBUCK 98            // coarse buckets of 512 nodes (98*512 = 50176)
#define BSHIFT 9
#define BCAP 10240          // bucket capacity (avg 8163, +25% margin)
#define NP1 195             // pass-1 blocks
#define EPB1 4104           // edges per pass-1 block (195*4104 >= 800000)

typedef __bf16 bf16_t;
typedef __bf16 bf16x8 __attribute__((ext_vector_type(8)));
typedef float floatx4 __attribute__((ext_vector_type(4)));

__device__ __forceinline__ float bfbits2f(unsigned int hi16) {
    union { unsigned int u; float f; } c; c.u = hi16; return c.f;
}
__device__ __forceinline__ unsigned short f2bfbits(float f) {
    bf16_t b = (bf16_t)f; unsigned short u;
    __builtin_memcpy(&u, &b, 2); return u;
}

// act: 0=none, 1=relu, 2=gelu(tanh-approx, fast exp), 3=softplus(fast)
__device__ __forceinline__ float act_rt(float v, int act) {
    if (act == 1) return fmaxf(v, 0.f);
    if (act == 2) {
        float w = 0.79788456f * (v + 0.044715f * v * v * v);
        float e = __expf(2.f * w);
        float th = 1.f - 2.f / (e + 1.f);
        return 0.5f * v * (1.f + th);
    }
    if (act == 3) return fmaxf(v, 0.f) + __logf(1.f + __expf(-fabsf(v)));
    return v;
}

// ---------------------------------------------------------------------------
// prep: blocks 0..8 transpose weights fp32->bf16; block 9 zeroes gcur
// ---------------------------------------------------------------------------
__global__ __launch_bounds__(256) void prep_w_zero(
    const float* __restrict__ w0, const float* __restrict__ w1,
    const float* __restrict__ w2, const float* __restrict__ w3,
    const float* __restrict__ w4, const float* __restrict__ w5,
    const float* __restrict__ w6, const float* __restrict__ w7,
    const float* __restrict__ w8, bf16_t* __restrict__ wt,
    int* __restrict__ gcur)
{
    if (blockIdx.x >= 9) {
        if (threadIdx.x < NBUCK) gcur[threadIdx.x] = 0;
        return;
    }
    const float* Ws[9] = {w0, w1, w2, w3, w4, w5, w6, w7, w8};
    const float* W = Ws[blockIdx.x];
    bf16_t* o = wt + blockIdx.x * 16384;
    for (int idx = threadIdx.x; idx < 16384; idx += 256) {
        int k = idx >> 7, n = idx & 127;
        o[n * 128 + k] = (bf16_t)W[idx];
    }
}

// ---------------------------------------------------------------------------
// GEMM building blocks, 64-row tile structure (48 KB LDS -> 3 blocks/CU).
// ---------------------------------------------------------------------------
__device__ __forceinline__ void load_w_regs(const bf16_t* __restrict__ W,
                                            uint4 (&wr)[8], int t)
{
    for (int i = 0; i < 8; ++i) {
        int c = t + i * 256;
        int row = c >> 4, g = c & 15;
        wr[i] = *(const uint4*)(W + row * 128 + g * 8);
    }
}
__device__ __forceinline__ void store_w_regs(const uint4 (&wr)[8],
                                             bf16_t* Bs, int t)
{
    for (int i = 0; i < 8; ++i) {
        int c = t + i * 256;
        int row = c >> 4, g = c & 15;
        *(uint4*)&Bs[row * 128 + ((g ^ (row & 15)) * 8)] = wr[i];
    }
}
__device__ __forceinline__ void afrag_gbf16(const bf16_t* __restrict__ A,
        bf16x8 (&af)[4], int r0, int lane, int wave, int M)
{
    int gr = r0 + wave * 16 + (lane & 15);
    gr = min(gr, M - 1);
    const bf16_t* p = A + (size_t)gr * 128 + (lane >> 4) * 8;
    for (int kc = 0; kc < 4; ++kc)
        af[kc] = *(const bf16x8*)(p + kc * 32);
}
__device__ __forceinline__ void kloop64(const bf16x8 (&af)[4], const bf16_t* Bs,
                                        floatx4 (&acc)[8], int l15, int quad)
{
    for (int ni = 0; ni < 8; ++ni)
        for (int r = 0; r < 4; ++r) acc[ni][r] = 0.f;
    for (int kc = 0; kc < 4; ++kc) {
        int kg = kc * 4 + quad;
        bf16x8 b[8];
        for (int ni = 0; ni < 8; ++ni) {
            int row = ni * 16 + l15;
            b[ni] = *(const bf16x8*)&Bs[row * 128 + ((kg ^ l15) * 8)];
        }
        for (int ni = 0; ni < 8; ++ni)
            acc[ni] = __builtin_amdgcn_mfma_f32_16x16x32_bf16(
                af[kc], b[ni], acc[ni], 0, 0, 0);
    }
}
__device__ __forceinline__ void write_Csw(bf16_t* Csw, floatx4 (&acc)[8],
        const float (&bias_r)[8], int lane, int wave, int act)
{
    const int l15 = lane & 15, quad = lane >> 4;
    for (int ni = 0; ni < 8; ++ni) {
        int col = ni * 16 + l15;
        for (int r = 0; r < 4; ++r) {
            int row = wave * 16 + quad * 4 + r;
            float v = act_rt(acc[ni][r] + bias_r[ni], act);
            Csw[row * 128 + (((col >> 3) ^ (row & 15)) << 3) + (col & 7)] = (bf16_t)v;
        }
    }
}
__device__ __forceinline__ void afrag_Csw(const bf16_t* Csw, bf16x8 (&af)[4],
                                          int lane, int wave)
{
    int l15 = lane & 15, quad = lane >> 4;
    int row = wave * 16 + l15;
    for (int kc = 0; kc < 4; ++kc) {
        int kg = kc * 4 + quad;
        af[kc] = *(const bf16x8*)&Csw[row * 128 + ((kg ^ l15) * 8)];
    }
}
__device__ __forceinline__ void copy_Csw_out(const bf16_t* Csw,
        bf16_t* __restrict__ out, int t, int r0, int M)
{
    for (int i = 0; i < 4; ++i) {
        int c = t + i * 256;
        int row = c >> 4, g = c & 15;
        int gr = r0 + row;
        if (gr < M)
            *(uint4*)(out + (size_t)gr * 128 + g * 8) =
                *(const uint4*)&Csw[row * 128 + ((g ^ (row & 15)) * 8)];
    }
}

// ---------------------------------------------------------------------------
// hln_p1: blocks with bid%5==4 run pass-1 edge binning (p1id = bid/5, 195
// blocks); the rest run h_ln tiles (tile = bid - bid/5, 782 tiles).
// ---------------------------------------------------------------------------
__global__ __launch_bounds__(256, 3) void hln_p1(
    const float* __restrict__ x, const bf16_t* __restrict__ wt,
    const float* __restrict__ b_lin,
    const float* __restrict__ ln_g, const float* __restrict__ ln_b,
    bf16_t* __restrict__ h, bf16_t* __restrict__ xres,
    const int* __restrict__ ei, int* __restrict__ gcur,
    unsigned* __restrict__ ebuf, int M)
{
    __shared__ __align__(16) char smem[49152];
    const int t = threadIdx.x;
    const int bid = blockIdx.x;

    if (bid % 5 == 4) {
        // ---- pass 1: bin EPB1 edges into coarse buckets ----
        int* lcnt  = (int*)smem;
        int* lbase = lcnt + NBUCK;
        if (t < NBUCK) lcnt[t] = 0;
        __syncthreads();
        int p1id = bid / 5;
        int base = p1id * EPB1;
        int e_end = min(base + EPB1, NEDGE);
        for (int e = base + t; e < e_end; e += 256)
            atomicAdd(&lcnt[ei[NEDGE + e] >> BSHIFT], 1);
        __syncthreads();
        if (t < NBUCK) {
            lbase[t] = atomicAdd(&gcur[t], lcnt[t]);
            lcnt[t] = 0;
        }
        __syncthreads();
        for (int e = base + t; e < e_end; e += 256) {
            int d = ei[NEDGE + e];
            int s = ei[e];
            int b = d >> BSHIFT;
            int off = atomicAdd(&lcnt[b], 1);
            int pos = lbase[b] + off;
            if (pos < BCAP)
                ebuf[(size_t)b * BCAP + pos] =
                    (unsigned)s | ((unsigned)(d & 511) << 16);
        }
        return;
    }

    // ---- h_ln tile ----
    bf16_t* Bs  = (bf16_t*)smem;
    bf16_t* Csw = (bf16_t*)(smem + 32768);
    const int tile = bid - bid / 5;
    const int r0 = tile * 64;
    const int lane = t & 63, wave = t >> 6, l15 = lane & 15, quad = lane >> 4;
    uint4 wr[8];
    bf16x8 af[4];
    floatx4 acc[8];
    float bias_r[8];
    for (int ni = 0; ni < 8; ++ni) bias_r[ni] = b_lin[ni * 16 + l15];

    {
        int gr = min(r0 + wave * 16 + l15, M - 1);
        const float* p = x + (size_t)gr * 128 + quad * 8;
        for (int kc = 0; kc < 4; ++kc) {
            float4 u0 = *(const float4*)(p + kc * 32);
            float4 u1 = *(const float4*)(p + kc * 32 + 4);
            bf16x8 f;
            f[0] = (bf16_t)u0.x; f[1] = (bf16_t)u0.y;
            f[2] = (bf16_t)u0.z; f[3] = (bf16_t)u0.w;
            f[4] = (bf16_t)u1.x; f[5] = (bf16_t)u1.y;
            f[6] = (bf16_t)u1.z; f[7] = (bf16_t)u1.w;
            af[kc] = f;
        }
    }
    load_w_regs(wt, wr, t);
    store_w_regs(wr, Bs, t);
    __syncthreads();
    kloop64(af, Bs, acc, l15, quad);
    write_Csw(Csw, acc, bias_r, lane, wave, 0);
    __syncthreads();

    int row = t >> 2, p4 = t & 3;
    int gr = r0 + row;
    uint4 raw[4];
    float vals[32];
    float s = 0.f, sq = 0.f;
    for (int i = 0; i < 4; ++i) {
        int lg = p4 * 4 + i;
        raw[i] = *(const uint4*)&Csw[row * 128 + ((lg ^ (row & 15)) * 8)];
        const unsigned* u = (const unsigned*)&raw[i];
        for (int k = 0; k < 4; ++k) {
            float f0 = bfbits2f(u[k] << 16);
            float f1 = bfbits2f(u[k] & 0xffff0000u);
            vals[i * 8 + k * 2] = f0; vals[i * 8 + k * 2 + 1] = f1;
            s += f0 + f1; sq += f0 * f0 + f1 * f1;
        }
    }
    s += __shfl_xor(s, 1, 64);  sq += __shfl_xor(sq, 1, 64);
    s += __shfl_xor(s, 2, 64);  sq += __shfl_xor(sq, 2, 64);
    float m   = s * (1.f / 128.f);
    float var = fmaxf(sq * (1.f / 128.f) - m * m, 0.f);
    float rs  = rsqrtf(var + 1e-5f);
    if (gr < M) {
        for (int i = 0; i < 4; ++i) {
            int lg = p4 * 4 + i;
            *(uint4*)(h + (size_t)gr * 128 + lg * 8) = raw[i];
            unsigned short ob[8];
            for (int k = 0; k < 8; ++k) {
                int col = lg * 8 + k;
                ob[k] = f2bfbits((vals[i * 8 + k] - m) * rs * ln_g[col] + ln_b[col]);
            }
            uint4 o;
            o.x = ob[0] | ((unsigned)ob[1] << 16);
            o.y = ob[2] | ((unsigned)ob[3] << 16);
            o.z = ob[4] | ((unsigned)ob[5] << 16);
            o.w = ob[6] | ((unsigned)ob[7] << 16);
            *(uint4*)(xres + (size_t)gr * 128 + lg * 8) = o;
        }
    }
}

// ---------------------------------------------------------------------------
// branch_p2: blocks with bid%25==24 run pass-2 CSR build (bucket = bid/25, 98
// blocks); the rest run branch tiles (tile = bid - bid/25; tiles >= 2346 idle).
// ---------------------------------------------------------------------------
__global__ __launch_bounds__(256, 3) void branch_p2(
    const bf16_t* __restrict__ h, const bf16_t* __restrict__ wt,
    const float* __restrict__ ba1, const float* __restrict__ ba2,
    const float* __restrict__ bb1, const float* __restrict__ bb2,
    const float* __restrict__ bg1, const float* __restrict__ bg2,
    bf16_t* __restrict__ al, bf16_t* __restrict__ be, bf16_t* __restrict__ ga,
    const int* __restrict__ gcur, const unsigned* __restrict__ ebuf,
    int* __restrict__ off_start, int* __restrict__ cntN,
    int* __restrict__ srcs, int M)
{
    __shared__ __align__(16) char smem[49152];
    const int t = threadIdx.x;
    const int bid = blockIdx.x;

    if (bid % 25 == 24) {
        // ---- pass 2: per-bucket exact CSR ----
        int* ncnt = (int*)smem;          // [512]
        int* sa   = ncnt + 512;          // [512] scan buf A
        int* sb   = sa + 512;            // [512] scan buf B
        int* ncur = sb + 512;            // [512]
        int* red  = ncur + 512;          // [4]
        const int b = bid / 25;
        int total = min(gcur[b], BCAP);

        // bucketBase = sum of clamped totals of buckets < b
        int v = 0;
        for (int j = t; j < b; j += 256) v += min(gcur[j], BCAP);
        for (int o = 1; o < 64; o <<= 1) v += __shfl_xor(v, o, 64);
        if ((t & 63) == 0) red[t >> 6] = v;
        ncnt[t] = 0; ncnt[t + 256] = 0;
        __syncthreads();
        int bucketBase = red[0] + red[1] + red[2] + red[3];

        const unsigned* eb = ebuf + (size_t)b * BCAP;
        for (int i = t; i < total; i += 256)
            atomicAdd(&ncnt[eb[i] >> 16], 1);
        __syncthreads();
        // inclusive Hillis-Steele scan over 512 (double buffer)
        sa[t] = ncnt[t]; sa[t + 256] = ncnt[t + 256];
        __syncthreads();
        int* pin = sa; int* pout = sb;
        for (int o = 1; o < 512; o <<= 1) {
            for (int j = t; j < 512; j += 256)
                pout[j] = pin[j] + (j >= o ? pin[j - o] : 0);
            __syncthreads();
            int* tmp = pin; pin = pout; pout = tmp;
        }
        // pin = inclusive scan
        for (int j = t; j < 512; j += 256) {
            int excl = pin[j] - ncnt[j];
            int node = (b << BSHIFT) + j;
            if (node < NODES) {
                off_start[node] = bucketBase + excl;
                cntN[node] = ncnt[j];
            }
            ncur[j] = excl;
        }
        __syncthreads();
        for (int i = t; i < total; i += 256) {
            unsigned p = eb[i];
            int dl = p >> 16;
            int pos = atomicAdd(&ncur[dl], 1);
            srcs[bucketBase + pos] = (int)(p & 0xFFFFu);
        }
        return;
    }

    // ---- branch tile ----
    const int tile = bid - bid / 25;
    if (tile >= 3 * NT_TILES) return;
    bf16_t* Bs  = (bf16_t*)smem;
    bf16_t* Csw = (bf16_t*)(smem + 32768);
    const int branch = tile / NT_TILES;
    const int r0 = (tile % NT_TILES) * 64;
    const int lane = t & 63, wave = t >> 6, l15 = lane & 15, quad = lane >> 4;
    uint4 wr[8];
    bf16x8 af[4];
    floatx4 acc[8];

    const bf16_t* w1 = wt + (1 + 2 * branch) * 16384;
    const bf16_t* w2 = wt + (2 + 2 * branch) * 16384;
    const float* b1p = (branch == 0) ? ba1 : (branch == 1) ? bb1 : bg1;
    const float* b2p = (branch == 0) ? ba2 : (branch == 1) ? bb2 : bg2;
    bf16_t* out = (branch == 0) ? al : (branch == 1) ? be : ga;
    const int act1 = (branch == 2) ? 2 : 1;
    const int act2 = (branch == 2) ? 0 : 3;

    float b1_r[8], b2_r[8];
    for (int ni = 0; ni < 8; ++ni) {
        b1_r[ni] = b1p[ni * 16 + l15];
        b2_r[ni] = b2p[ni * 16 + l15];
    }

    afrag_gbf16(h, af, r0, lane, wave, M);
    load_w_regs(w1, wr, t);
    store_w_regs(wr, Bs, t);
    load_w_regs(w2, wr, t);                  // prefetch second weight
    __syncthreads();

    kloop64(af, Bs, acc, l15, quad);
    write_Csw(Csw, acc, b1_r, lane, wave, act1);
    __syncthreads();
    store_w_regs(wr, Bs, t);                 // Bs <- W2
    __syncthreads();

    afrag_Csw(Csw, af, lane, wave);
    kloop64(af, Bs, acc, l15, quad);
    __syncthreads();
    write_Csw(Csw, acc, b2_r, lane, wave, act2);
    __syncthreads();
    copy_Csw_out(Csw, out, t, r0, M);
}

// ---------------------------------------------------------------------------
// Kernel C: z = gelu(y@Wf1+bf1)@Wf2 + bf2 + xres -> out fp32
// ---------------------------------------------------------------------------
__global__ __launch_bounds__(256, 3) void fused_out(
    const bf16_t* __restrict__ y, const bf16_t* __restrict__ wt,
    const float* __restrict__ bf1, const float* __restrict__ bf2,
    const bf16_t* __restrict__ xres, float* __restrict__ out, int M)
{
    __shared__ __align__(16) char smem[49152];
    bf16_t* Bs  = (bf16_t*)smem;
    bf16_t* Csw = (bf16_t*)(smem + 32768);
    float*  Cf  = (float*)smem;
    const int t = threadIdx.x;
    const int r0 = blockIdx.x * 64;
    const int lane = t & 63, wave = t >> 6, l15 = lane & 15, quad = lane >> 4;
    uint4 wr[8];
    bf16x8 af[4];
    floatx4 acc[8];

    float b1_r[8], b2_r[8];
    for (int ni = 0; ni < 8; ++ni) {
        b1_r[ni] = bf1[ni * 16 + l15];
        b2_r[ni] = bf2[ni * 16 + l15];
    }

    afrag_gbf16(y, af, r0, lane, wave, M);
    load_w_regs(wt + 7 * 16384, wr, t);
    store_w_regs(wr, Bs, t);
    load_w_regs(wt + 8 * 16384, wr, t);
    __syncthreads();

    kloop64(af, Bs, acc, l15, quad);
    write_Csw(Csw, acc, b1_r, lane, wave, 2);   // gelu
    __syncthreads();
    store_w_regs(wr, Bs, t);
    __syncthreads();

    afrag_Csw(Csw, af, lane, wave);
    kloop64(af, Bs, acc, l15, quad);
    __syncthreads();

    for (int ni = 0; ni < 8; ++ni) {
        int col = ni * 16 + l15;
        for (int r = 0; r < 4; ++r) {
            int row = wave * 16 + quad * 4 + r;
            Cf[row * 132 + col] = acc[ni][r] + b2_r[ni];
        }
    }
    __syncthreads();
    for (int i = 0; i < 8; ++i) {
        int c = t + i * 256;
        int row = c >> 5, q = c & 31;
        int gr = r0 + row;
        if (gr < M) {
            float4 v = *(const float4*)&Cf[row * 132 + q * 4];
            uint2 xr = *(const uint2*)(xres + (size_t)gr * 128 + q * 4);
            v.x += bfbits2f(xr.x << 16);
            v.y += bfbits2f(xr.x & 0xffff0000u);
            v.z += bfbits2f(xr.y << 16);
            v.w += bfbits2f(xr.y & 0xffff0000u);
            *(float4*)(out + (size_t)gr * 128 + q * 4) = v;
        }
    }
}

// ---------------------------------------------------------------------------
// Gather + y: one wave per node; quad-parallel 16B row loads
// ---------------------------------------------------------------------------
__global__ __launch_bounds__(256) void gather_y_kernel(
    const int* __restrict__ off_start, const int* __restrict__ cnt,
    const int* __restrict__ srcs, const bf16_t* __restrict__ h,
    const bf16_t* __restrict__ al, const bf16_t* __restrict__ be,
    const bf16_t* __restrict__ ga, const float* __restrict__ deg,
    bf16_t* __restrict__ y, int M)
{
    int wave = threadIdx.x >> 6, lane = threadIdx.x & 63;
    int node = blockIdx.x * 4 + wave;
    if (node >= M) return;
    int s0 = __builtin_amdgcn_readfirstlane(off_start[node]);
    int n  = __builtin_amdgcn_readfirstlane(cnt[node]);
    int grp = lane >> 4, c16 = lane & 15;
    float a[8] = {0.f, 0.f, 0.f, 0.f, 0.f, 0.f, 0.f, 0.f};

    for (int j = 0; j < n; j += 8) {
        int e0 = j + grp, e1 = j + 4 + grp;
        int i0 = srcs[s0 + min(e0, n - 1)];
        int i1 = srcs[s0 + min(e1, n - 1)];
        uint4 v0 = *(const uint4*)(h + (size_t)i0 * 128 + c16 * 8);
        uint4 v1 = *(const uint4*)(h + (size_t)i1 * 128 + c16 * 8);
        if (e0 < n) {
            const unsigned* u = (const unsigned*)&v0;
            for (int k = 0; k < 4; ++k) {
                a[2 * k]     += bfbits2f(u[k] << 16);
                a[2 * k + 1] += bfbits2f(u[k] & 0xffff0000u);
            }
        }
        if (e1 < n) {
            const unsigned* u = (const unsigned*)&v1;
            for (int k = 0; k < 4; ++k) {
                a[2 * k]     += bfbits2f(u[k] << 16);
                a[2 * k + 1] += bfbits2f(u[k] & 0xffff0000u);
            }
        }
    }
    for (int k = 0; k < 8; ++k) {
        a[k] += __shfl_xor(a[k], 16, 64);
        a[k] += __shfl_xor(a[k], 32, 64);
    }
    if (lane < 16) {
        size_t i0 = (size_t)node * 128 + (size_t)c16 * 8;
        uint4 ra = *(const uint4*)(al + i0);
        uint4 rb = *(const uint4*)(be + i0);
        uint4 rg = *(const uint4*)(ga + i0);
        float d = deg[node];
        const unsigned* ua = (const unsigned*)&ra;
        const unsigned* ub = (const unsigned*)&rb;
        const unsigned* ug = (const unsigned*)&rg;
        unsigned short o[8];
        for (int k = 0; k < 4; ++k) {
            float a0 = bfbits2f(ua[k] << 16), a1 = bfbits2f(ua[k] & 0xffff0000u);
            float b0 = bfbits2f(ub[k] << 16), b1 = bfbits2f(ub[k] & 0xffff0000u);
            float g0 = bfbits2f(ug[k] << 16), g1 = bfbits2f(ug[k] & 0xffff0000u);
            o[2 * k]     = f2bfbits((b0 * a[2 * k]     + g0) / (a0 + b0 * d));
            o[2 * k + 1] = f2bfbits((b1 * a[2 * k + 1] + g1) / (a1 + b1 * d));
        }
        uint4 ov;
        ov.x = o[0] | ((unsigned)o[1] << 16);
        ov.y = o[2] | ((unsigned)o[3] << 16);
        ov.z = o[4] | ((unsigned)o[5] << 16);
        ov.w = o[6] | ((unsigned)o[7] << 16);
        *(uint4*)(y + i0) = ov;
    }
}

// ---------------------------------------------------------------------------
extern "C" void kernel_launch(void* const* d_in, const int* in_sizes, int n_in,
                              void* d_out, int out_size, void* d_ws, size_t ws_size,
                              hipStream_t stream)
{
    const float* x    = (const float*)d_in[0];
    const int*   ei   = (const int*)d_in[1];
    const float* deg  = (const float*)d_in[2];
    const float* W_lin = (const float*)d_in[3];  const float* b_lin = (const float*)d_in[4];
    const float* Wa1 = (const float*)d_in[5];    const float* ba1 = (const float*)d_in[6];
    const float* Wa2 = (const float*)d_in[7];    const float* ba2 = (const float*)d_in[8];
    const float* Wb1 = (const float*)d_in[9];    const float* bb1 = (const float*)d_in[10];
    const float* Wb2 = (const float*)d_in[11];   const float* bb2 = (const float*)d_in[12];
    const float* Wg1 = (const float*)d_in[13];   const float* bg1 = (const float*)d_in[14];
    const float* Wg2 = (const float*)d_in[15];   const float* bg2 = (const float*)d_in[16];
    const float* Wf1 = (const float*)d_in[17];   const float* bf1 = (const float*)d_in[18];
    const float* Wf2 = (const float*)d_in[19];   const float* bf2 = (const float*)d_in[20];
    const float* ln_g = (const float*)d_in[21];  const float* ln_b = (const float*)d_in[22];

    const int M = NODES;
    const size_t NB2 = (size_t)M * 128 * 2;   // bf16 [N,128]

    char* ws = (char*)d_ws;
    size_t off = 0;
    bf16_t* wt  = (bf16_t*)(ws + off); off += (size_t)9 * 16384 * 2;
    bf16_t* h   = (bf16_t*)(ws + off); off += NB2;
    bf16_t* al  = (bf16_t*)(ws + off); off += NB2;
    bf16_t* be  = (bf16_t*)(ws + off); off += NB2;
    bf16_t* ga  = (bf16_t*)(ws + off); off += NB2;
    bf16_t* yv  = (bf16_t*)(ws + off); off += NB2;
    bf16_t* xres = (bf16_t*)(ws + off); off += NB2;
    int* gcur      = (int*)(ws + off); off += 128 * 4;
    int* off_start = (int*)(ws + off); off += (size_t)NODES * 4 + 64;
    int* cntN      = (int*)(ws + off); off += (size_t)NODES * 4 + 64;
    int* srcs      = (int*)(ws + off); off += (size_t)NEDGE * 4;
    unsigned* ebuf = (unsigned*)(ws + off); off += (size_t)NBUCK * BCAP * 4;
    float* outp = (float*)d_out;

    dim3 blk(256);

    // weights transpose + gcur zero
    prep_w_zero<<<10, blk, 0, stream>>>(
        W_lin, Wa1, Wa2, Wb1, Wb2, Wg1, Wg2, Wf1, Wf2, wt, gcur);

    // h/LN co-launched with pass-1 edge binning (782 tiles + 195 p1 blocks)
    hln_p1<<<977, blk, 0, stream>>>(
        x, wt, b_lin, ln_g, ln_b, h, xres, ei, gcur, ebuf, M);

    // branches co-launched with pass-2 CSR build (2346 tiles + 98 p2 blocks)
    branch_p2<<<2450, blk, 0, stream>>>(
        h, wt, ba1, ba2, bb1, bb2, bg1, bg2, al, be, ga,
        gcur, ebuf, off_start, cntN, srcs, M);

    // gather + y
    gather_y_kernel<<<(M + 3) / 4, blk, 0, stream>>>(off_start, cntN, srcs, h,
                                                     al, be, ga, deg, yv, M);
    // final MLP + residual
    fused_out<<<NT_TILES, blk, 0, stream>>>(yv, wt, bf1, bf2, xres, outp, M);
}